// Round 2
// baseline (2237.458 us; speedup 1.0000x reference)
//
#include <hip/hip_runtime.h>
#include <stdint.h>

typedef __bf16 bf16;
typedef __bf16 bf16x4 __attribute__((ext_vector_type(4)));
typedef __bf16 bf16x8 __attribute__((ext_vector_type(8)));
typedef float f32x4 __attribute__((ext_vector_type(4)));

#define MFMA16(a, b, c) __builtin_amdgcn_mfma_f32_16x16x32_bf16((a), (b), (c), 0, 0, 0)

static constexpr int NB = 4;      // batch
static constexpr int NH = 16;     // heads
static constexpr int SL = 2048;   // seq len
static constexpr int HD = 64;     // head dim
static constexpr int ED = 1024;   // embed
static constexpr int MR = NB * SL; // 8192 rows

__device__ __forceinline__ void gl_lds16(const void* g, void* l) {
    __builtin_amdgcn_global_load_lds(
        (const __attribute__((address_space(1))) unsigned int*)g,
        (__attribute__((address_space(3))) unsigned int*)l, 16, 0, 0);
}

// ------------------- f32 -> bf16 hi/lo split -------------------
__global__ void k_split(const float* __restrict__ src, bf16* __restrict__ hi,
                        bf16* __restrict__ lo, int n4) {
    int i = blockIdx.x * blockDim.x + threadIdx.x;
    if (i >= n4) return;
    const float4 v = ((const float4*)src)[i];
    float vv[4] = {v.x, v.y, v.z, v.w};
    bf16x4 hv, lv;
#pragma unroll
    for (int e = 0; e < 4; ++e) {
        bf16 h = (bf16)vv[e];
        hv[e] = h;
        lv[e] = (bf16)(vv[e] - (float)h);
    }
    ((bf16x4*)hi)[i] = hv;
    ((bf16x4*)lo)[i] = lv;
}

// ------------------- QKV projection GEMM (hi/lo) -------------------
// C[m,e] = sum_i x[m,i]*W[e,i] + b[e]; 128x128 tile, BK=32, 4 waves.
__global__ __launch_bounds__(256) void k_qkv_gemm(
    const bf16* __restrict__ xh, const bf16* __restrict__ xl,
    const bf16* __restrict__ wh, const bf16* __restrict__ wl,
    const float* __restrict__ bq, const float* __restrict__ bk,
    const float* __restrict__ bv,
    bf16* __restrict__ qh, bf16* __restrict__ ql,
    bf16* __restrict__ kh, bf16* __restrict__ kl, bf16* __restrict__ vh)
{
    __shared__ __attribute__((aligned(16))) bf16 As[2][128 * 32];
    __shared__ __attribute__((aligned(16))) bf16 Bs[2][128 * 32];

    const int z  = blockIdx.z;           // 0=q,1=k,2=v
    const int m0 = blockIdx.x * 128;
    const int n0 = blockIdx.y * 128;
    const int tid = threadIdx.x, wave = tid >> 6, lane = tid & 63;
    const int wr = wave >> 1, wc = wave & 1;
    const int fr = lane & 15, fq = lane >> 4;
    const bf16* Wh = wh + (size_t)z * ED * ED;
    const bf16* Wl = wl + (size_t)z * ED * ED;

    const f32x4 z4 = {0.f, 0.f, 0.f, 0.f};
    f32x4 acc[4][4];
#pragma unroll
    for (int i = 0; i < 4; ++i)
#pragma unroll
        for (int j = 0; j < 4; ++j) acc[i][j] = z4;

#pragma unroll 1
    for (int kk = 0; kk < ED; kk += 32) {
#pragma unroll
        for (int r = 0; r < 2; ++r) {
            const int chunk = r * 256 + tid;
            const int row = chunk >> 2, c8 = (chunk & 3) * 8;
            const size_t ax = (size_t)(m0 + row) * ED + kk + c8;
            const size_t bx = (size_t)(n0 + row) * ED + kk + c8;
            const int db = (r * 256 + wave * 64) * 8;   // wave-uniform LDS base
            gl_lds16(xh + ax, &As[0][db]);
            gl_lds16(xl + ax, &As[1][db]);
            gl_lds16(Wh + bx, &Bs[0][db]);
            gl_lds16(Wl + bx, &Bs[1][db]);
        }
        __syncthreads();
        bf16x8 af[4][2], bfg[4][2];
#pragma unroll
        for (int i = 0; i < 4; ++i) {
            const int arow = wr * 64 + i * 16 + fr;
            af[i][0] = *(const bf16x8*)&As[0][arow * 32 + fq * 8];
            af[i][1] = *(const bf16x8*)&As[1][arow * 32 + fq * 8];
            const int brow = wc * 64 + i * 16 + fr;
            bfg[i][0] = *(const bf16x8*)&Bs[0][brow * 32 + fq * 8];
            bfg[i][1] = *(const bf16x8*)&Bs[1][brow * 32 + fq * 8];
        }
#pragma unroll
        for (int mi = 0; mi < 4; ++mi)
#pragma unroll
            for (int ni = 0; ni < 4; ++ni) {
                acc[mi][ni] = MFMA16(af[mi][0], bfg[ni][0], acc[mi][ni]);
                acc[mi][ni] = MFMA16(af[mi][0], bfg[ni][1], acc[mi][ni]);
                acc[mi][ni] = MFMA16(af[mi][1], bfg[ni][0], acc[mi][ni]);
            }
        __syncthreads();
    }

    const float* bias = (z == 0) ? bq : (z == 1) ? bk : bv;
#pragma unroll
    for (int mi = 0; mi < 4; ++mi) {
#pragma unroll
        for (int ni = 0; ni < 4; ++ni) {
            const int col = n0 + wc * 64 + ni * 16 + fr;
            const int hh = col >> 6, dd = col & 63;
#pragma unroll
            for (int j = 0; j < 4; ++j) {
                const int row = m0 + wr * 64 + mi * 16 + fq * 4 + j;
                float v = acc[mi][ni][j] + bias[col];
                const int nb = row >> 11, li = row & (SL - 1);
                const size_t off = (((size_t)nb * NH + hh) * SL + li) * HD + dd;
                if (z == 0) {
                    v *= 0.125f;                       // head_dim^-0.5
                    bf16 hv = (bf16)v;
                    qh[off] = hv; ql[off] = (bf16)(v - (float)hv);
                } else if (z == 1) {
                    bf16 hv = (bf16)v;
                    kh[off] = hv; kl[off] = (bf16)(v - (float)hv);
                } else {
                    vh[off] = (bf16)v;
                }
            }
        }
    }
}

// ------------------- output projection GEMM (hi/lo) -------------------
__global__ __launch_bounds__(256) void k_out_gemm(
    const bf16* __restrict__ ah, const bf16* __restrict__ al,
    const bf16* __restrict__ wh, const bf16* __restrict__ wl,
    const float* __restrict__ bo, float* __restrict__ out)
{
    __shared__ __attribute__((aligned(16))) bf16 As[2][128 * 32];
    __shared__ __attribute__((aligned(16))) bf16 Bs[2][128 * 32];

    const int m0 = blockIdx.x * 128;
    const int n0 = blockIdx.y * 128;
    const int tid = threadIdx.x, wave = tid >> 6, lane = tid & 63;
    const int wr = wave >> 1, wc = wave & 1;
    const int fr = lane & 15, fq = lane >> 4;

    const f32x4 z4 = {0.f, 0.f, 0.f, 0.f};
    f32x4 acc[4][4];
#pragma unroll
    for (int i = 0; i < 4; ++i)
#pragma unroll
        for (int j = 0; j < 4; ++j) acc[i][j] = z4;

#pragma unroll 1
    for (int kk = 0; kk < ED; kk += 32) {
#pragma unroll
        for (int r = 0; r < 2; ++r) {
            const int chunk = r * 256 + tid;
            const int row = chunk >> 2, c8 = (chunk & 3) * 8;
            const size_t ax = (size_t)(m0 + row) * ED + kk + c8;
            const size_t bx = (size_t)(n0 + row) * ED + kk + c8;
            const int db = (r * 256 + wave * 64) * 8;
            gl_lds16(ah + ax, &As[0][db]);
            gl_lds16(al + ax, &As[1][db]);
            gl_lds16(wh + bx, &Bs[0][db]);
            gl_lds16(wl + bx, &Bs[1][db]);
        }
        __syncthreads();
        bf16x8 af[4][2], bfg[4][2];
#pragma unroll
        for (int i = 0; i < 4; ++i) {
            const int arow = wr * 64 + i * 16 + fr;
            af[i][0] = *(const bf16x8*)&As[0][arow * 32 + fq * 8];
            af[i][1] = *(const bf16x8*)&As[1][arow * 32 + fq * 8];
            const int brow = wc * 64 + i * 16 + fr;
            bfg[i][0] = *(const bf16x8*)&Bs[0][brow * 32 + fq * 8];
            bfg[i][1] = *(const bf16x8*)&Bs[1][brow * 32 + fq * 8];
        }
#pragma unroll
        for (int mi = 0; mi < 4; ++mi)
#pragma unroll
            for (int ni = 0; ni < 4; ++ni) {
                acc[mi][ni] = MFMA16(af[mi][0], bfg[ni][0], acc[mi][ni]);
                acc[mi][ni] = MFMA16(af[mi][0], bfg[ni][1], acc[mi][ni]);
                acc[mi][ni] = MFMA16(af[mi][1], bfg[ni][0], acc[mi][ni]);
            }
        __syncthreads();
    }

#pragma unroll
    for (int mi = 0; mi < 4; ++mi)
#pragma unroll
        for (int ni = 0; ni < 4; ++ni) {
            const int col = n0 + wc * 64 + ni * 16 + fr;
#pragma unroll
            for (int j = 0; j < 4; ++j) {
                const int row = m0 + wr * 64 + mi * 16 + fq * 4 + j;
                out[(size_t)row * ED + col] = acc[mi][ni][j] + bo[col];
            }
        }
}

// ------------------- flash attention (per n,h,64-row q tile) -------------------
__global__ __launch_bounds__(256) void k_flash(
    const bf16* __restrict__ qh, const bf16* __restrict__ ql,
    const bf16* __restrict__ kh, const bf16* __restrict__ kl,
    const bf16* __restrict__ vh,
    const float* __restrict__ bias, const int* __restrict__ mask,
    bf16* __restrict__ ch, bf16* __restrict__ cl,
    float* __restrict__ mrow, float* __restrict__ srow)
{
    __shared__ __attribute__((aligned(16))) bf16 vT[64 * 80];      // [d][k] padded
    __shared__ __attribute__((aligned(16))) bf16 wls[4][16 * 80];  // per-wave weights

    const int qt = blockIdx.x, h = blockIdx.y, n = blockIdx.z;
    const int tid = threadIdx.x, wave = tid >> 6, lane = tid & 63;
    const int fr = lane & 15, fq = lane >> 4;
    const int q0 = qt * 64;
    const size_t hoff = ((size_t)n * NH + h) * SL * HD;
    const f32x4 z4 = {0.f, 0.f, 0.f, 0.f};

    // q fragments (persist whole kernel)
    bf16x8 qfh[2], qfl[2];
    {
        const size_t qb = hoff + (size_t)(q0 + wave * 16 + fr) * HD + fq * 8;
        qfh[0] = *(const bf16x8*)(qh + qb);
        qfh[1] = *(const bf16x8*)(qh + qb + 32);
        qfl[0] = *(const bf16x8*)(ql + qb);
        qfl[1] = *(const bf16x8*)(ql + qb + 32);
    }

    f32x4 o[4];
#pragma unroll
    for (int f = 0; f < 4; ++f) o[f] = z4;
    float mj[4] = {-3e38f, -3e38f, -3e38f, -3e38f};
    float sj[4] = {0.f, 0.f, 0.f, 0.f};
    size_t brow[4];
#pragma unroll
    for (int j = 0; j < 4; ++j)
        brow[j] = ((size_t)h * SL + q0 + wave * 16 + fq * 4 + j) * SL;
    const int* mkb = mask + n * SL;

#pragma unroll 1
    for (int kt = 0; kt < 32; ++kt) {
        const int k0 = kt * 64;
        // stage V transposed into LDS: vT[d][k]
#pragma unroll
        for (int r = 0; r < 2; ++r) {
            const int c8 = r * 4 + wave;
            const bf16x8 v8 = *(const bf16x8*)(vh + hoff + (size_t)(k0 + lane) * HD + c8 * 8);
#pragma unroll
            for (int e = 0; e < 8; ++e)
                vT[(c8 * 8 + e) * 80 + lane] = v8[e];
        }
        __syncthreads();

        // scores: 16 q rows x 64 k cols per wave (hi/lo MFMA)
        f32x4 sf[4];
#pragma unroll
        for (int nf = 0; nf < 4; ++nf) {
            const size_t kb = hoff + (size_t)(k0 + nf * 16 + fr) * HD + fq * 8;
            const bf16x8 b0h = *(const bf16x8*)(kh + kb);
            const bf16x8 b1h = *(const bf16x8*)(kh + kb + 32);
            const bf16x8 b0l = *(const bf16x8*)(kl + kb);
            const bf16x8 b1l = *(const bf16x8*)(kl + kb + 32);
            f32x4 a = z4;
            a = MFMA16(qfh[0], b0h, a);
            a = MFMA16(qfh[0], b0l, a);
            a = MFMA16(qfl[0], b0h, a);
            a = MFMA16(qfh[1], b1h, a);
            a = MFMA16(qfh[1], b1l, a);
            a = MFMA16(qfl[1], b1h, a);
            sf[nf] = a;
        }
        // bias + mask
#pragma unroll
        for (int nf = 0; nf < 4; ++nf) {
            const int kc = k0 + nf * 16 + fr;
            const bool mk = mkb[kc] != 0;
#pragma unroll
            for (int j = 0; j < 4; ++j) {
                float s = sf[nf][j] + bias[brow[j] + kc];
                sf[nf][j] = mk ? -1e30f : s;
            }
        }
        // online softmax (rows are wave-local; reduce across 16-lane groups)
        float tmax[4];
#pragma unroll
        for (int j = 0; j < 4; ++j)
            tmax[j] = fmaxf(fmaxf(sf[0][j], sf[1][j]), fmaxf(sf[2][j], sf[3][j]));
#pragma unroll
        for (int d = 1; d < 16; d <<= 1)
#pragma unroll
            for (int j = 0; j < 4; ++j)
                tmax[j] = fmaxf(tmax[j], __shfl_xor(tmax[j], d));
        float scale[4];
#pragma unroll
        for (int j = 0; j < 4; ++j) {
            const float mn = fmaxf(mj[j], tmax[j]);
            scale[j] = __expf(mj[j] - mn);
            mj[j] = mn;
        }
        float rs[4] = {0.f, 0.f, 0.f, 0.f};
#pragma unroll
        for (int nf = 0; nf < 4; ++nf)
#pragma unroll
            for (int j = 0; j < 4; ++j) {
                const float w = __expf(sf[nf][j] - mj[j]);
                sf[nf][j] = w;
                rs[j] += w;
            }
#pragma unroll
        for (int d = 1; d < 16; d <<= 1)
#pragma unroll
            for (int j = 0; j < 4; ++j)
                rs[j] += __shfl_xor(rs[j], d);
#pragma unroll
        for (int j = 0; j < 4; ++j) sj[j] = sj[j] * scale[j] + rs[j];
#pragma unroll
        for (int f = 0; f < 4; ++f)
#pragma unroll
            for (int j = 0; j < 4; ++j) o[f][j] *= scale[j];
        // weights -> per-wave LDS tile (C-layout -> A-layout redistribution)
#pragma unroll
        for (int nf = 0; nf < 4; ++nf)
#pragma unroll
            for (int j = 0; j < 4; ++j)
                wls[wave][(fq * 4 + j) * 80 + nf * 16 + fr] = (bf16)sf[nf][j];
        // PV
        const bf16x8 wa0 = *(const bf16x8*)&wls[wave][fr * 80 + fq * 8];
        const bf16x8 wa1 = *(const bf16x8*)&wls[wave][fr * 80 + 32 + fq * 8];
#pragma unroll
        for (int f = 0; f < 4; ++f) {
            const bf16x8 vb0 = *(const bf16x8*)&vT[(f * 16 + fr) * 80 + fq * 8];
            const bf16x8 vb1 = *(const bf16x8*)&vT[(f * 16 + fr) * 80 + 32 + fq * 8];
            o[f] = MFMA16(wa0, vb0, o[f]);
            o[f] = MFMA16(wa1, vb1, o[f]);
        }
        __syncthreads();
    }

    // epilogue: context (hi/lo) + row stats
#pragma unroll
    for (int j = 0; j < 4; ++j) {
        const float inv = 1.0f / sj[j];
        const int row = n * SL + q0 + wave * 16 + fq * 4 + j;
#pragma unroll
        for (int f = 0; f < 4; ++f) {
            const float v = o[f][j] * inv;
            const size_t off = (size_t)row * ED + h * HD + f * 16 + fr;
            const bf16 hv = (bf16)v;
            ch[off] = hv;
            cl[off] = (bf16)(v - (float)hv);
        }
    }
    if (fr == 0) {
#pragma unroll
        for (int j = 0; j < 4; ++j) {
            const int r = q0 + wave * 16 + fq * 4 + j;
            mrow[((size_t)n * NH + h) * SL + r] = mj[j];
            srow[((size_t)n * NH + h) * SL + r] = sj[j];
        }
    }
}

// ------------------- head-averaged weights -------------------
__global__ __launch_bounds__(256) void k_avg(
    const bf16* __restrict__ qh, const bf16* __restrict__ ql,
    const bf16* __restrict__ kh, const bf16* __restrict__ kl,
    const float* __restrict__ bias, const int* __restrict__ mask,
    const float* __restrict__ mrow, const float* __restrict__ srow,
    float* __restrict__ avg)
{
    const int qt = blockIdx.x, kt = blockIdx.y;
    const int tid = threadIdx.x, wave = tid >> 6, lane = tid & 63;
    const int fr = lane & 15, fq = lane >> 4;
    const int q0 = qt * 64, k0 = kt * 64;
    const int qr = q0 + wave * 16;
    const f32x4 z4 = {0.f, 0.f, 0.f, 0.f};

    float acc[4][4][4] = {};   // [n][nf][j]
    bool mk[4][4];
#pragma unroll
    for (int nn = 0; nn < 4; ++nn)
#pragma unroll
        for (int nf = 0; nf < 4; ++nf)
            mk[nn][nf] = mask[nn * SL + k0 + nf * 16 + fr] != 0;

#pragma unroll 1
    for (int h = 0; h < NH; ++h) {
        float bfr[4][4];
#pragma unroll
        for (int nf = 0; nf < 4; ++nf)
#pragma unroll
            for (int j = 0; j < 4; ++j)
                bfr[nf][j] = bias[((size_t)h * SL + qr + fq * 4 + j) * SL + k0 + nf * 16 + fr];
#pragma unroll 1
        for (int nn = 0; nn < 4; ++nn) {
            const size_t hoff = ((size_t)nn * NH + h) * SL * HD;
            const size_t qb = hoff + (size_t)(qr + fr) * HD + fq * 8;
            const bf16x8 qfh0 = *(const bf16x8*)(qh + qb);
            const bf16x8 qfh1 = *(const bf16x8*)(qh + qb + 32);
            const bf16x8 qfl0 = *(const bf16x8*)(ql + qb);
            const bf16x8 qfl1 = *(const bf16x8*)(ql + qb + 32);
            float mv[4], inv[4];
#pragma unroll
            for (int j = 0; j < 4; ++j) {
                const size_t sidx = ((size_t)nn * NH + h) * SL + qr + fq * 4 + j;
                mv[j] = mrow[sidx];
                inv[j] = 1.0f / (16.0f * srow[sidx]);
            }
#pragma unroll
            for (int nf = 0; nf < 4; ++nf) {
                const size_t kb = hoff + (size_t)(k0 + nf * 16 + fr) * HD + fq * 8;
                const bf16x8 b0h = *(const bf16x8*)(kh + kb);
                const bf16x8 b1h = *(const bf16x8*)(kh + kb + 32);
                const bf16x8 b0l = *(const bf16x8*)(kl + kb);
                const bf16x8 b1l = *(const bf16x8*)(kl + kb + 32);
                f32x4 a = z4;
                a = MFMA16(qfh0, b0h, a);
                a = MFMA16(qfh0, b0l, a);
                a = MFMA16(qfl0, b0h, a);
                a = MFMA16(qfh1, b1h, a);
                a = MFMA16(qfh1, b1l, a);
                a = MFMA16(qfl1, b1h, a);
#pragma unroll
                for (int j = 0; j < 4; ++j) {
                    const float w = mk[nn][nf] ? 0.f
                        : __expf(a[j] + bfr[nf][j] - mv[j]) * inv[j];
                    acc[nn][nf][j] += w;
                }
            }
        }
    }
#pragma unroll
    for (int nn = 0; nn < 4; ++nn)
#pragma unroll
        for (int j = 0; j < 4; ++j) {
            const size_t rowoff = ((size_t)nn * SL + qr + fq * 4 + j) * SL;
#pragma unroll
            for (int nf = 0; nf < 4; ++nf)
                avg[rowoff + k0 + nf * 16 + fr] = acc[nn][nf][j];
        }
}

// ------------------- launcher -------------------
extern "C" void kernel_launch(void* const* d_in, const int* in_sizes, int n_in,
                              void* d_out, int out_size, void* d_ws, size_t ws_size,
                              hipStream_t stream)
{
    (void)in_sizes; (void)n_in; (void)out_size; (void)ws_size;
    const float* query = (const float*)d_in[0];
    const float* bias  = (const float*)d_in[1];
    const int* mask = (const int*)d_in[2];
    const float* Wq = (const float*)d_in[3];
    const float* bq = (const float*)d_in[4];
    const float* Wk = (const float*)d_in[5];
    const float* bk = (const float*)d_in[6];
    const float* Wv = (const float*)d_in[7];
    const float* bv = (const float*)d_in[8];
    const float* Wo = (const float*)d_in[9];
    const float* bo = (const float*)d_in[10];
    float* out0 = (float*)d_out;                      // [N,L,E]
    float* out1 = out0 + (size_t)MR * ED;             // [N,L,L]

    char* p = (char*)d_ws;
    auto carve = [&](size_t bytes) {
        char* r = p;
        p += (bytes + 255) & ~(size_t)255;
        return r;
    };
    const size_t QKVB = (size_t)NB * NH * SL * HD * 2;   // 16.78 MB
    bf16* xh = (bf16*)carve((size_t)MR * ED * 2);
    bf16* xl = (bf16*)carve((size_t)MR * ED * 2);
    bf16* wh = (bf16*)carve((size_t)4 * ED * ED * 2);
    bf16* wl = (bf16*)carve((size_t)4 * ED * ED * 2);
    bf16* qh = (bf16*)carve(QKVB);
    bf16* ql = (bf16*)carve(QKVB);
    bf16* kh = (bf16*)carve(QKVB);
    bf16* kl = (bf16*)carve(QKVB);
    bf16* vh = (bf16*)carve(QKVB);
    float* mrow = (float*)carve((size_t)NB * NH * SL * 4);
    float* srow = (float*)carve((size_t)NB * NH * SL * 4);
    bf16* ch = (bf16*)carve((size_t)MR * ED * 2);
    bf16* cl = (bf16*)carve((size_t)MR * ED * 2);

    // 1. split inputs to hi/lo bf16
    {
        const int n4 = MR * ED / 4;
        k_split<<<(n4 + 255) / 256, 256, 0, stream>>>(query, xh, xl, n4);
        const int w4 = ED * ED / 4;
        const float* Ws[4] = {Wq, Wk, Wv, Wo};
        for (int i = 0; i < 4; ++i)
            k_split<<<(w4 + 255) / 256, 256, 0, stream>>>(
                Ws[i], wh + (size_t)i * ED * ED, wl + (size_t)i * ED * ED, w4);
    }
    // 2. QKV projections
    k_qkv_gemm<<<dim3(MR / 128, ED / 128, 3), 256, 0, stream>>>(
        xh, xl, wh, wl, bq, bk, bv, qh, ql, kh, kl, vh);
    // 3. flash attention + row stats + context
    k_flash<<<dim3(SL / 64, NH, NB), 256, 0, stream>>>(
        qh, ql, kh, kl, vh, bias, mask, ch, cl, mrow, srow);
    // 4. head-averaged attention weights
    k_avg<<<dim3(SL / 64, SL / 64), 256, 0, stream>>>(
        qh, ql, kh, kl, bias, mask, mrow, srow, out1);
    // 5. output projection
    k_out_gemm<<<dim3(MR / 128, ED / 128), 256, 0, stream>>>(
        ch, cl, wh + (size_t)3 * ED * ED, wl + (size_t)3 * ED * ED, bo, out0);
}

// Round 3
// 1457.519 us; speedup vs baseline: 1.5351x; 1.5351x over previous
//
#include <hip/hip_runtime.h>
#include <stdint.h>

typedef __bf16 bf16;
typedef __bf16 bf16x4 __attribute__((ext_vector_type(4)));
typedef __bf16 bf16x8 __attribute__((ext_vector_type(8)));
typedef float f32x4 __attribute__((ext_vector_type(4)));

#define MFMA16(a, b, c) __builtin_amdgcn_mfma_f32_16x16x32_bf16((a), (b), (c), 0, 0, 0)

static constexpr int NB = 4;      // batch
static constexpr int NH = 16;     // heads
static constexpr int SL = 2048;   // seq len
static constexpr int HD = 64;     // head dim
static constexpr int ED = 1024;   // embed
static constexpr int MR = NB * SL; // 8192 rows

__device__ __forceinline__ void gl_lds16(const void* g, void* l) {
    __builtin_amdgcn_global_load_lds(
        (const __attribute__((address_space(1))) unsigned int*)g,
        (__attribute__((address_space(3))) unsigned int*)l, 16, 0, 0);
}

// ------------------- f32 -> bf16 hi/lo split -------------------
__global__ void k_split(const float* __restrict__ src, bf16* __restrict__ hi,
                        bf16* __restrict__ lo, int n4) {
    int i = blockIdx.x * blockDim.x + threadIdx.x;
    if (i >= n4) return;
    const float4 v = ((const float4*)src)[i];
    float vv[4] = {v.x, v.y, v.z, v.w};
    bf16x4 hv, lv;
#pragma unroll
    for (int e = 0; e < 4; ++e) {
        bf16 h = (bf16)vv[e];
        hv[e] = h;
        lv[e] = (bf16)(vv[e] - (float)h);
    }
    ((bf16x4*)hi)[i] = hv;
    ((bf16x4*)lo)[i] = lv;
}

// ------------------- QKV projection GEMM (hi/lo) -------------------
// C[m,e] = sum_i x[m,i]*W[e,i] + b[e]; 128x128 tile, BK=32, 4 waves.
__global__ __launch_bounds__(256) void k_qkv_gemm(
    const bf16* __restrict__ xh, const bf16* __restrict__ xl,
    const bf16* __restrict__ wh, const bf16* __restrict__ wl,
    const float* __restrict__ bq, const float* __restrict__ bk,
    const float* __restrict__ bv,
    bf16* __restrict__ qh, bf16* __restrict__ ql,
    bf16* __restrict__ kh, bf16* __restrict__ kl, bf16* __restrict__ vh)
{
    __shared__ __attribute__((aligned(16))) bf16 As[2][128 * 32];
    __shared__ __attribute__((aligned(16))) bf16 Bs[2][128 * 32];

    const int z  = blockIdx.z;           // 0=q,1=k,2=v
    const int m0 = blockIdx.x * 128;
    const int n0 = blockIdx.y * 128;
    const int tid = threadIdx.x, wave = tid >> 6, lane = tid & 63;
    const int wr = wave >> 1, wc = wave & 1;
    const int fr = lane & 15, fq = lane >> 4;
    const bf16* Wh = wh + (size_t)z * ED * ED;
    const bf16* Wl = wl + (size_t)z * ED * ED;

    const f32x4 z4 = {0.f, 0.f, 0.f, 0.f};
    f32x4 acc[4][4];
#pragma unroll
    for (int i = 0; i < 4; ++i)
#pragma unroll
        for (int j = 0; j < 4; ++j) acc[i][j] = z4;

#pragma unroll 1
    for (int kk = 0; kk < ED; kk += 32) {
#pragma unroll
        for (int r = 0; r < 2; ++r) {
            const int chunk = r * 256 + tid;
            const int row = chunk >> 2, c8 = (chunk & 3) * 8;
            const size_t ax = (size_t)(m0 + row) * ED + kk + c8;
            const size_t bx = (size_t)(n0 + row) * ED + kk + c8;
            const int db = (r * 256 + wave * 64) * 8;   // wave-uniform LDS base
            gl_lds16(xh + ax, &As[0][db]);
            gl_lds16(xl + ax, &As[1][db]);
            gl_lds16(Wh + bx, &Bs[0][db]);
            gl_lds16(Wl + bx, &Bs[1][db]);
        }
        __syncthreads();
        bf16x8 af[4][2], bfg[4][2];
#pragma unroll
        for (int i = 0; i < 4; ++i) {
            const int arow = wr * 64 + i * 16 + fr;
            af[i][0] = *(const bf16x8*)&As[0][arow * 32 + fq * 8];
            af[i][1] = *(const bf16x8*)&As[1][arow * 32 + fq * 8];
            const int brow = wc * 64 + i * 16 + fr;
            bfg[i][0] = *(const bf16x8*)&Bs[0][brow * 32 + fq * 8];
            bfg[i][1] = *(const bf16x8*)&Bs[1][brow * 32 + fq * 8];
        }
#pragma unroll
        for (int mi = 0; mi < 4; ++mi)
#pragma unroll
            for (int ni = 0; ni < 4; ++ni) {
                acc[mi][ni] = MFMA16(af[mi][0], bfg[ni][0], acc[mi][ni]);
                acc[mi][ni] = MFMA16(af[mi][0], bfg[ni][1], acc[mi][ni]);
                acc[mi][ni] = MFMA16(af[mi][1], bfg[ni][0], acc[mi][ni]);
            }
        __syncthreads();
    }

    const float* bias = (z == 0) ? bq : (z == 1) ? bk : bv;
#pragma unroll
    for (int mi = 0; mi < 4; ++mi) {
#pragma unroll
        for (int ni = 0; ni < 4; ++ni) {
            const int col = n0 + wc * 64 + ni * 16 + fr;
            const int hh = col >> 6, dd = col & 63;
#pragma unroll
            for (int j = 0; j < 4; ++j) {
                const int row = m0 + wr * 64 + mi * 16 + fq * 4 + j;
                float v = acc[mi][ni][j] + bias[col];
                const int nb = row >> 11, li = row & (SL - 1);
                const size_t off = (((size_t)nb * NH + hh) * SL + li) * HD + dd;
                if (z == 0) {
                    v *= 0.125f;                       // head_dim^-0.5
                    bf16 hv = (bf16)v;
                    qh[off] = hv; ql[off] = (bf16)(v - (float)hv);
                } else if (z == 1) {
                    bf16 hv = (bf16)v;
                    kh[off] = hv; kl[off] = (bf16)(v - (float)hv);
                } else {
                    vh[off] = (bf16)v;
                }
            }
        }
    }
}

// ------------------- output projection GEMM (hi/lo) -------------------
__global__ __launch_bounds__(256) void k_out_gemm(
    const bf16* __restrict__ ah, const bf16* __restrict__ al,
    const bf16* __restrict__ wh, const bf16* __restrict__ wl,
    const float* __restrict__ bo, float* __restrict__ out)
{
    __shared__ __attribute__((aligned(16))) bf16 As[2][128 * 32];
    __shared__ __attribute__((aligned(16))) bf16 Bs[2][128 * 32];

    const int m0 = blockIdx.x * 128;
    const int n0 = blockIdx.y * 128;
    const int tid = threadIdx.x, wave = tid >> 6, lane = tid & 63;
    const int wr = wave >> 1, wc = wave & 1;
    const int fr = lane & 15, fq = lane >> 4;

    const f32x4 z4 = {0.f, 0.f, 0.f, 0.f};
    f32x4 acc[4][4];
#pragma unroll
    for (int i = 0; i < 4; ++i)
#pragma unroll
        for (int j = 0; j < 4; ++j) acc[i][j] = z4;

#pragma unroll 1
    for (int kk = 0; kk < ED; kk += 32) {
#pragma unroll
        for (int r = 0; r < 2; ++r) {
            const int chunk = r * 256 + tid;
            const int row = chunk >> 2, c8 = (chunk & 3) * 8;
            const size_t ax = (size_t)(m0 + row) * ED + kk + c8;
            const size_t bx = (size_t)(n0 + row) * ED + kk + c8;
            const int db = (r * 256 + wave * 64) * 8;
            gl_lds16(ah + ax, &As[0][db]);
            gl_lds16(al + ax, &As[1][db]);
            gl_lds16(wh + bx, &Bs[0][db]);
            gl_lds16(wl + bx, &Bs[1][db]);
        }
        __syncthreads();
        bf16x8 af[4][2], bfg[4][2];
#pragma unroll
        for (int i = 0; i < 4; ++i) {
            const int arow = wr * 64 + i * 16 + fr;
            af[i][0] = *(const bf16x8*)&As[0][arow * 32 + fq * 8];
            af[i][1] = *(const bf16x8*)&As[1][arow * 32 + fq * 8];
            const int brow = wc * 64 + i * 16 + fr;
            bfg[i][0] = *(const bf16x8*)&Bs[0][brow * 32 + fq * 8];
            bfg[i][1] = *(const bf16x8*)&Bs[1][brow * 32 + fq * 8];
        }
#pragma unroll
        for (int mi = 0; mi < 4; ++mi)
#pragma unroll
            for (int ni = 0; ni < 4; ++ni) {
                acc[mi][ni] = MFMA16(af[mi][0], bfg[ni][0], acc[mi][ni]);
                acc[mi][ni] = MFMA16(af[mi][0], bfg[ni][1], acc[mi][ni]);
                acc[mi][ni] = MFMA16(af[mi][1], bfg[ni][0], acc[mi][ni]);
            }
        __syncthreads();
    }

#pragma unroll
    for (int mi = 0; mi < 4; ++mi)
#pragma unroll
        for (int ni = 0; ni < 4; ++ni) {
            const int col = n0 + wc * 64 + ni * 16 + fr;
#pragma unroll
            for (int j = 0; j < 4; ++j) {
                const int row = m0 + wr * 64 + mi * 16 + fq * 4 + j;
                out[(size_t)row * ED + col] = acc[mi][ni][j] + bo[col];
            }
        }
}

// ------------------- flash attention (per n,h,64-row q tile) -------------------
__global__ __launch_bounds__(256) void k_flash(
    const bf16* __restrict__ qh, const bf16* __restrict__ ql,
    const bf16* __restrict__ kh, const bf16* __restrict__ kl,
    const bf16* __restrict__ vh,
    const float* __restrict__ bias, const int* __restrict__ mask,
    bf16* __restrict__ ch, bf16* __restrict__ cl,
    float* __restrict__ mrow, float* __restrict__ srow)
{
    __shared__ __attribute__((aligned(16))) bf16 vT[64 * 80];      // [d][k] padded
    __shared__ __attribute__((aligned(16))) bf16 wls[4][16 * 80];  // per-wave weights

    const int qt = blockIdx.x, h = blockIdx.y, n = blockIdx.z;
    const int tid = threadIdx.x, wave = tid >> 6, lane = tid & 63;
    const int fr = lane & 15, fq = lane >> 4;
    const int q0 = qt * 64;
    const size_t hoff = ((size_t)n * NH + h) * SL * HD;
    const f32x4 z4 = {0.f, 0.f, 0.f, 0.f};

    // q fragments (persist whole kernel)
    bf16x8 qfh[2], qfl[2];
    {
        const size_t qb = hoff + (size_t)(q0 + wave * 16 + fr) * HD + fq * 8;
        qfh[0] = *(const bf16x8*)(qh + qb);
        qfh[1] = *(const bf16x8*)(qh + qb + 32);
        qfl[0] = *(const bf16x8*)(ql + qb);
        qfl[1] = *(const bf16x8*)(ql + qb + 32);
    }

    f32x4 o[4];
#pragma unroll
    for (int f = 0; f < 4; ++f) o[f] = z4;
    float mj[4] = {-3e38f, -3e38f, -3e38f, -3e38f};
    float sj[4] = {0.f, 0.f, 0.f, 0.f};
    size_t brow[4];
#pragma unroll
    for (int j = 0; j < 4; ++j)
        brow[j] = ((size_t)h * SL + q0 + wave * 16 + fq * 4 + j) * SL;
    const int* mkb = mask + n * SL;

#pragma unroll 1
    for (int kt = 0; kt < 32; ++kt) {
        const int k0 = kt * 64;
        // stage V transposed into LDS: vT[d][k]
#pragma unroll
        for (int r = 0; r < 2; ++r) {
            const int c8 = r * 4 + wave;
            const bf16x8 v8 = *(const bf16x8*)(vh + hoff + (size_t)(k0 + lane) * HD + c8 * 8);
#pragma unroll
            for (int e = 0; e < 8; ++e)
                vT[(c8 * 8 + e) * 80 + lane] = v8[e];
        }
        __syncthreads();

        // scores: 16 q rows x 64 k cols per wave (hi/lo MFMA)
        f32x4 sf[4];
#pragma unroll
        for (int nf = 0; nf < 4; ++nf) {
            const size_t kb = hoff + (size_t)(k0 + nf * 16 + fr) * HD + fq * 8;
            const bf16x8 b0h = *(const bf16x8*)(kh + kb);
            const bf16x8 b1h = *(const bf16x8*)(kh + kb + 32);
            const bf16x8 b0l = *(const bf16x8*)(kl + kb);
            const bf16x8 b1l = *(const bf16x8*)(kl + kb + 32);
            f32x4 a = z4;
            a = MFMA16(qfh[0], b0h, a);
            a = MFMA16(qfh[0], b0l, a);
            a = MFMA16(qfl[0], b0h, a);
            a = MFMA16(qfh[1], b1h, a);
            a = MFMA16(qfh[1], b1l, a);
            a = MFMA16(qfl[1], b1h, a);
            sf[nf] = a;
        }
        // bias + mask
#pragma unroll
        for (int nf = 0; nf < 4; ++nf) {
            const int kc = k0 + nf * 16 + fr;
            const bool mk = mkb[kc] != 0;
#pragma unroll
            for (int j = 0; j < 4; ++j) {
                float s = sf[nf][j] + bias[brow[j] + kc];
                sf[nf][j] = mk ? -1e30f : s;
            }
        }
        // online softmax (rows are wave-local; reduce across 16-lane groups)
        float tmax[4];
#pragma unroll
        for (int j = 0; j < 4; ++j)
            tmax[j] = fmaxf(fmaxf(sf[0][j], sf[1][j]), fmaxf(sf[2][j], sf[3][j]));
#pragma unroll
        for (int d = 1; d < 16; d <<= 1)
#pragma unroll
            for (int j = 0; j < 4; ++j)
                tmax[j] = fmaxf(tmax[j], __shfl_xor(tmax[j], d));
        float scale[4];
#pragma unroll
        for (int j = 0; j < 4; ++j) {
            const float mn = fmaxf(mj[j], tmax[j]);
            scale[j] = __expf(mj[j] - mn);
            mj[j] = mn;
        }
        float rs[4] = {0.f, 0.f, 0.f, 0.f};
#pragma unroll
        for (int nf = 0; nf < 4; ++nf)
#pragma unroll
            for (int j = 0; j < 4; ++j) {
                const float w = __expf(sf[nf][j] - mj[j]);
                sf[nf][j] = w;
                rs[j] += w;
            }
#pragma unroll
        for (int d = 1; d < 16; d <<= 1)
#pragma unroll
            for (int j = 0; j < 4; ++j)
                rs[j] += __shfl_xor(rs[j], d);
#pragma unroll
        for (int j = 0; j < 4; ++j) sj[j] = sj[j] * scale[j] + rs[j];
#pragma unroll
        for (int f = 0; f < 4; ++f)
#pragma unroll
            for (int j = 0; j < 4; ++j) o[f][j] *= scale[j];
        // weights -> per-wave LDS tile (C-layout -> A-layout redistribution)
#pragma unroll
        for (int nf = 0; nf < 4; ++nf)
#pragma unroll
            for (int j = 0; j < 4; ++j)
                wls[wave][(fq * 4 + j) * 80 + nf * 16 + fr] = (bf16)sf[nf][j];
        // PV
        const bf16x8 wa0 = *(const bf16x8*)&wls[wave][fr * 80 + fq * 8];
        const bf16x8 wa1 = *(const bf16x8*)&wls[wave][fr * 80 + 32 + fq * 8];
#pragma unroll
        for (int f = 0; f < 4; ++f) {
            const bf16x8 vb0 = *(const bf16x8*)&vT[(f * 16 + fr) * 80 + fq * 8];
            const bf16x8 vb1 = *(const bf16x8*)&vT[(f * 16 + fr) * 80 + 32 + fq * 8];
            o[f] = MFMA16(wa0, vb0, o[f]);
            o[f] = MFMA16(wa1, vb1, o[f]);
        }
        __syncthreads();
    }

    // epilogue: context (hi/lo) + row stats
#pragma unroll
    for (int j = 0; j < 4; ++j) {
        const float inv = 1.0f / sj[j];
        const int row = n * SL + q0 + wave * 16 + fq * 4 + j;
#pragma unroll
        for (int f = 0; f < 4; ++f) {
            const float v = o[f][j] * inv;
            const size_t off = (size_t)row * ED + h * HD + f * 16 + fr;
            const bf16 hv = (bf16)v;
            ch[off] = hv;
            cl[off] = (bf16)(v - (float)hv);
        }
    }
    if (fr == 0) {
#pragma unroll
        for (int j = 0; j < 4; ++j) {
            const int r = q0 + wave * 16 + fq * 4 + j;
            mrow[((size_t)n * NH + h) * SL + r] = mj[j];
            srow[((size_t)n * NH + h) * SL + r] = sj[j];
        }
    }
}

// ------------------- head-averaged weights (LDS accumulator, bf16-hi scores) -------------------
__global__ __launch_bounds__(256) void k_avg(
    const bf16* __restrict__ qh, const bf16* __restrict__ kh,
    const float* __restrict__ bias, const int* __restrict__ mask,
    const float* __restrict__ mrow, const float* __restrict__ srow,
    float* __restrict__ avg)
{
    constexpr int RS = 66;                       // row stride (floats): fq bank shift = 8
    __shared__ float accS[4 * 64 * RS];          // 67.6 KB: [nn][qrow(64)][kcol(64)+pad]

    const int qt = blockIdx.x, kt = blockIdx.y;
    const int tid = threadIdx.x, wave = tid >> 6, lane = tid & 63;
    const int fr = lane & 15, fq = lane >> 4;
    const int q0 = qt * 64, k0 = kt * 64;
    const int qr = q0 + wave * 16;
    const f32x4 z4 = {0.f, 0.f, 0.f, 0.f};

    for (int i = tid; i < 4 * 64 * RS; i += 256) accS[i] = 0.f;

    bool mk[4][4];
#pragma unroll
    for (int nn = 0; nn < 4; ++nn)
#pragma unroll
        for (int nf = 0; nf < 4; ++nf)
            mk[nn][nf] = mask[nn * SL + k0 + nf * 16 + fr] != 0;
    __syncthreads();

#pragma unroll 1
    for (int h = 0; h < NH; ++h) {
        float bfr[4][4];
#pragma unroll
        for (int nf = 0; nf < 4; ++nf)
#pragma unroll
            for (int j = 0; j < 4; ++j)
                bfr[nf][j] = bias[((size_t)h * SL + qr + fq * 4 + j) * SL + k0 + nf * 16 + fr];
#pragma unroll 1
        for (int nn = 0; nn < 4; ++nn) {
            const size_t hoff = ((size_t)nn * NH + h) * SL * HD;
            const size_t qb = hoff + (size_t)(qr + fr) * HD + fq * 8;
            const bf16x8 qf0 = *(const bf16x8*)(qh + qb);
            const bf16x8 qf1 = *(const bf16x8*)(qh + qb + 32);
            float mv[4], inv[4];
#pragma unroll
            for (int j = 0; j < 4; ++j) {
                const size_t sidx = ((size_t)nn * NH + h) * SL + qr + fq * 4 + j;
                mv[j] = mrow[sidx];
                inv[j] = 1.0f / (16.0f * srow[sidx]);
            }
#pragma unroll
            for (int nf = 0; nf < 4; ++nf) {
                const size_t kb = hoff + (size_t)(k0 + nf * 16 + fr) * HD + fq * 8;
                const bf16x8 b0 = *(const bf16x8*)(kh + kb);
                const bf16x8 b1 = *(const bf16x8*)(kh + kb + 32);
                f32x4 a = z4;
                a = MFMA16(qf0, b0, a);
                a = MFMA16(qf1, b1, a);
                float* ap = &accS[((nn * 64 + wave * 16 + fq * 4) * RS) + nf * 16 + fr];
#pragma unroll
                for (int j = 0; j < 4; ++j) {
                    const float w = mk[nn][nf] ? 0.f
                        : __expf(a[j] + bfr[nf][j] - mv[j]) * inv[j];
                    ap[j * RS] += w;
                }
            }
        }
    }
    __syncthreads();

    // coalesced writeback: 16 (nn,row) pairs per pass, 16 lanes x f32x4 per row
#pragma unroll 1
    for (int p = 0; p < 16; ++p) {
        const int pair = p * 16 + (tid >> 4);
        const int nn = pair >> 6, row = pair & 63;
        const int c = (tid & 15) * 4;
        const float* src = &accS[(nn * 64 + row) * RS + c];
        f32x4 v = {src[0], src[1], src[2], src[3]};
        *(f32x4*)&avg[((size_t)nn * SL + q0 + row) * SL + k0 + c] = v;
    }
}

// ------------------- launcher -------------------
extern "C" void kernel_launch(void* const* d_in, const int* in_sizes, int n_in,
                              void* d_out, int out_size, void* d_ws, size_t ws_size,
                              hipStream_t stream)
{
    (void)in_sizes; (void)n_in; (void)out_size; (void)ws_size;
    const float* query = (const float*)d_in[0];
    const float* bias  = (const float*)d_in[1];
    const int* mask = (const int*)d_in[2];
    const float* Wq = (const float*)d_in[3];
    const float* bq = (const float*)d_in[4];
    const float* Wk = (const float*)d_in[5];
    const float* bk = (const float*)d_in[6];
    const float* Wv = (const float*)d_in[7];
    const float* bv = (const float*)d_in[8];
    const float* Wo = (const float*)d_in[9];
    const float* bo = (const float*)d_in[10];
    float* out0 = (float*)d_out;                      // [N,L,E]
    float* out1 = out0 + (size_t)MR * ED;             // [N,L,L]

    char* p = (char*)d_ws;
    auto carve = [&](size_t bytes) {
        char* r = p;
        p += (bytes + 255) & ~(size_t)255;
        return r;
    };
    const size_t QKVB = (size_t)NB * NH * SL * HD * 2;   // 16.78 MB
    bf16* xh = (bf16*)carve((size_t)MR * ED * 2);
    bf16* xl = (bf16*)carve((size_t)MR * ED * 2);
    bf16* wh = (bf16*)carve((size_t)4 * ED * ED * 2);
    bf16* wl = (bf16*)carve((size_t)4 * ED * ED * 2);
    bf16* qh = (bf16*)carve(QKVB);
    bf16* ql = (bf16*)carve(QKVB);
    bf16* kh = (bf16*)carve(QKVB);
    bf16* kl = (bf16*)carve(QKVB);
    bf16* vh = (bf16*)carve(QKVB);
    float* mrow = (float*)carve((size_t)NB * NH * SL * 4);
    float* srow = (float*)carve((size_t)NB * NH * SL * 4);
    bf16* ch = (bf16*)carve((size_t)MR * ED * 2);
    bf16* cl = (bf16*)carve((size_t)MR * ED * 2);

    // 1. split inputs to hi/lo bf16
    {
        const int n4 = MR * ED / 4;
        k_split<<<(n4 + 255) / 256, 256, 0, stream>>>(query, xh, xl, n4);
        const int w4 = ED * ED / 4;
        const float* Ws[4] = {Wq, Wk, Wv, Wo};
        for (int i = 0; i < 4; ++i)
            k_split<<<(w4 + 255) / 256, 256, 0, stream>>>(
                Ws[i], wh + (size_t)i * ED * ED, wl + (size_t)i * ED * ED, w4);
    }
    // 2. QKV projections
    k_qkv_gemm<<<dim3(MR / 128, ED / 128, 3), 256, 0, stream>>>(
        xh, xl, wh, wl, bq, bk, bv, qh, ql, kh, kl, vh);
    // 3. flash attention + row stats + context
    k_flash<<<dim3(SL / 64, NH, NB), 256, 0, stream>>>(
        qh, ql, kh, kl, vh, bias, mask, ch, cl, mrow, srow);
    // 4. head-averaged attention weights
    k_avg<<<dim3(SL / 64, SL / 64), 256, 0, stream>>>(
        qh, kh, bias, mask, mrow, srow, out1);
    // 5. output projection
    k_out_gemm<<<dim3(MR / 128, ED / 128), 256, 0, stream>>>(
        ch, cl, wh + (size_t)3 * ED * ED, wl + (size_t)3 * ED * ED, bo, out0);
}

// Round 5
// 967.685 us; speedup vs baseline: 2.3122x; 1.5062x over previous
//
#include <hip/hip_runtime.h>
#include <stdint.h>

typedef __bf16 bf16;
typedef __bf16 bf16x4 __attribute__((ext_vector_type(4)));
typedef __bf16 bf16x8 __attribute__((ext_vector_type(8)));
typedef float f32x4 __attribute__((ext_vector_type(4)));

#define MFMA16(a, b, c) __builtin_amdgcn_mfma_f32_16x16x32_bf16((a), (b), (c), 0, 0, 0)

static constexpr int NB = 4;      // batch
static constexpr int NH = 16;     // heads
static constexpr int SL = 2048;   // seq len
static constexpr int HD = 64;     // head dim
static constexpr int ED = 1024;   // embed
static constexpr int MR = NB * SL; // 8192 rows

__device__ __forceinline__ void gl_lds16(const void* g, void* l) {
    __builtin_amdgcn_global_load_lds(
        (const __attribute__((address_space(1))) unsigned int*)g,
        (__attribute__((address_space(3))) unsigned int*)l, 16, 0, 0);
}

// ------------------- f32 -> bf16 hi/lo split -------------------
__global__ void k_split(const float* __restrict__ src, bf16* __restrict__ hi,
                        bf16* __restrict__ lo, int n4) {
    int i = blockIdx.x * blockDim.x + threadIdx.x;
    if (i >= n4) return;
    const float4 v = ((const float4*)src)[i];
    float vv[4] = {v.x, v.y, v.z, v.w};
    bf16x4 hv, lv;
#pragma unroll
    for (int e = 0; e < 4; ++e) {
        bf16 h = (bf16)vv[e];
        hv[e] = h;
        lv[e] = (bf16)(vv[e] - (float)h);
    }
    ((bf16x4*)hi)[i] = hv;
    ((bf16x4*)lo)[i] = lv;
}

// ------------------- QKV projection GEMM (hi/lo inputs, bf16 outputs) -------------------
__global__ __launch_bounds__(256) void k_qkv_gemm(
    const bf16* __restrict__ xh, const bf16* __restrict__ xl,
    const bf16* __restrict__ wh, const bf16* __restrict__ wl,
    const float* __restrict__ bq, const float* __restrict__ bk,
    const float* __restrict__ bv,
    bf16* __restrict__ qh, bf16* __restrict__ kh, bf16* __restrict__ vh)
{
    __shared__ __attribute__((aligned(16))) bf16 As[2][128 * 32];
    __shared__ __attribute__((aligned(16))) bf16 Bs[2][128 * 32];

    const int z  = blockIdx.z;           // 0=q,1=k,2=v
    const int m0 = blockIdx.x * 128;
    const int n0 = blockIdx.y * 128;
    const int tid = threadIdx.x, wave = tid >> 6, lane = tid & 63;
    const int wr = wave >> 1, wc = wave & 1;
    const int fr = lane & 15, fq = lane >> 4;
    const bf16* Wh = wh + (size_t)z * ED * ED;
    const bf16* Wl = wl + (size_t)z * ED * ED;

    const f32x4 z4 = {0.f, 0.f, 0.f, 0.f};
    f32x4 acc[4][4];
#pragma unroll
    for (int i = 0; i < 4; ++i)
#pragma unroll
        for (int j = 0; j < 4; ++j) acc[i][j] = z4;

#pragma unroll 1
    for (int kk = 0; kk < ED; kk += 32) {
#pragma unroll
        for (int r = 0; r < 2; ++r) {
            const int chunk = r * 256 + tid;
            const int row = chunk >> 2, c8 = (chunk & 3) * 8;
            const size_t ax = (size_t)(m0 + row) * ED + kk + c8;
            const size_t bx = (size_t)(n0 + row) * ED + kk + c8;
            const int db = (r * 256 + wave * 64) * 8;   // wave-uniform LDS base
            gl_lds16(xh + ax, &As[0][db]);
            gl_lds16(xl + ax, &As[1][db]);
            gl_lds16(Wh + bx, &Bs[0][db]);
            gl_lds16(Wl + bx, &Bs[1][db]);
        }
        __syncthreads();
        bf16x8 af[4][2], bfg[4][2];
#pragma unroll
        for (int i = 0; i < 4; ++i) {
            const int arow = wr * 64 + i * 16 + fr;
            af[i][0] = *(const bf16x8*)&As[0][arow * 32 + fq * 8];
            af[i][1] = *(const bf16x8*)&As[1][arow * 32 + fq * 8];
            const int brow = wc * 64 + i * 16 + fr;
            bfg[i][0] = *(const bf16x8*)&Bs[0][brow * 32 + fq * 8];
            bfg[i][1] = *(const bf16x8*)&Bs[1][brow * 32 + fq * 8];
        }
#pragma unroll
        for (int mi = 0; mi < 4; ++mi)
#pragma unroll
            for (int ni = 0; ni < 4; ++ni) {
                acc[mi][ni] = MFMA16(af[mi][0], bfg[ni][0], acc[mi][ni]);
                acc[mi][ni] = MFMA16(af[mi][0], bfg[ni][1], acc[mi][ni]);
                acc[mi][ni] = MFMA16(af[mi][1], bfg[ni][0], acc[mi][ni]);
            }
        __syncthreads();
    }

    const float* bias = (z == 0) ? bq : (z == 1) ? bk : bv;
#pragma unroll
    for (int mi = 0; mi < 4; ++mi) {
#pragma unroll
        for (int ni = 0; ni < 4; ++ni) {
            const int col = n0 + wc * 64 + ni * 16 + fr;
            const int hh = col >> 6, dd = col & 63;
#pragma unroll
            for (int j = 0; j < 4; ++j) {
                const int row = m0 + wr * 64 + mi * 16 + fq * 4 + j;
                float v = acc[mi][ni][j] + bias[col];
                const int nb = row >> 11, li = row & (SL - 1);
                const size_t off = (((size_t)nb * NH + hh) * SL + li) * HD + dd;
                if (z == 0) {
                    qh[off] = (bf16)(v * 0.125f);      // head_dim^-0.5
                } else if (z == 1) {
                    kh[off] = (bf16)v;
                } else {
                    vh[off] = (bf16)v;
                }
            }
        }
    }
}

// ------------------- output projection GEMM (hi/lo) -------------------
__global__ __launch_bounds__(256) void k_out_gemm(
    const bf16* __restrict__ ah, const bf16* __restrict__ al,
    const bf16* __restrict__ wh, const bf16* __restrict__ wl,
    const float* __restrict__ bo, float* __restrict__ out)
{
    __shared__ __attribute__((aligned(16))) bf16 As[2][128 * 32];
    __shared__ __attribute__((aligned(16))) bf16 Bs[2][128 * 32];

    const int m0 = blockIdx.x * 128;
    const int n0 = blockIdx.y * 128;
    const int tid = threadIdx.x, wave = tid >> 6, lane = tid & 63;
    const int wr = wave >> 1, wc = wave & 1;
    const int fr = lane & 15, fq = lane >> 4;

    const f32x4 z4 = {0.f, 0.f, 0.f, 0.f};
    f32x4 acc[4][4];
#pragma unroll
    for (int i = 0; i < 4; ++i)
#pragma unroll
        for (int j = 0; j < 4; ++j) acc[i][j] = z4;

#pragma unroll 1
    for (int kk = 0; kk < ED; kk += 32) {
#pragma unroll
        for (int r = 0; r < 2; ++r) {
            const int chunk = r * 256 + tid;
            const int row = chunk >> 2, c8 = (chunk & 3) * 8;
            const size_t ax = (size_t)(m0 + row) * ED + kk + c8;
            const size_t bx = (size_t)(n0 + row) * ED + kk + c8;
            const int db = (r * 256 + wave * 64) * 8;
            gl_lds16(ah + ax, &As[0][db]);
            gl_lds16(al + ax, &As[1][db]);
            gl_lds16(wh + bx, &Bs[0][db]);
            gl_lds16(wl + bx, &Bs[1][db]);
        }
        __syncthreads();
        bf16x8 af[4][2], bfg[4][2];
#pragma unroll
        for (int i = 0; i < 4; ++i) {
            const int arow = wr * 64 + i * 16 + fr;
            af[i][0] = *(const bf16x8*)&As[0][arow * 32 + fq * 8];
            af[i][1] = *(const bf16x8*)&As[1][arow * 32 + fq * 8];
            const int brow = wc * 64 + i * 16 + fr;
            bfg[i][0] = *(const bf16x8*)&Bs[0][brow * 32 + fq * 8];
            bfg[i][1] = *(const bf16x8*)&Bs[1][brow * 32 + fq * 8];
        }
#pragma unroll
        for (int mi = 0; mi < 4; ++mi)
#pragma unroll
            for (int ni = 0; ni < 4; ++ni) {
                acc[mi][ni] = MFMA16(af[mi][0], bfg[ni][0], acc[mi][ni]);
                acc[mi][ni] = MFMA16(af[mi][0], bfg[ni][1], acc[mi][ni]);
                acc[mi][ni] = MFMA16(af[mi][1], bfg[ni][0], acc[mi][ni]);
            }
        __syncthreads();
    }

#pragma unroll
    for (int mi = 0; mi < 4; ++mi)
#pragma unroll
        for (int ni = 0; ni < 4; ++ni) {
            const int col = n0 + wc * 64 + ni * 16 + fr;
#pragma unroll
            for (int j = 0; j < 4; ++j) {
                const int row = m0 + wr * 64 + mi * 16 + fq * 4 + j;
                out[(size_t)row * ED + col] = acc[mi][ni][j] + bo[col];
            }
        }
}

// ------------------- flash attention v2.1 -------------------
// One block per (n,h,64-row q-tile). K staged via global_load_lds (linear dest,
// inverse-swizzled source); V transposed + P tile written at XOR-swizzled slots
// (chunk ^= row&7 within 128B rows). Depth-1 prefetch, ONE barrier per K-tile.
__global__ __launch_bounds__(256) void k_flash(
    const bf16* __restrict__ qh, const bf16* __restrict__ kh,
    const bf16* __restrict__ vh,
    const float* __restrict__ bias, const int* __restrict__ mask,
    bf16* __restrict__ ch, bf16* __restrict__ cl,
    float* __restrict__ mrow, float* __restrict__ srow)
{
    __shared__ __attribute__((aligned(16))) bf16 Ks[2][64 * 64];  // [key][d] swz
    __shared__ __attribute__((aligned(16))) bf16 Vs[2][64 * 64];  // [d][key] swz
    __shared__ __attribute__((aligned(16))) bf16 Ws[4][16 * 64];  // per-wave P, swz

    // XCD-chunked swizzle: each XCD gets 256 consecutive wg = 8 full (n,h) groups
    const int bid = blockIdx.x;
    const int wg = (bid & 7) * 256 + (bid >> 3);
    const int qt = wg & 31, h = (wg >> 5) & 15, n = wg >> 9;

    const int tid = threadIdx.x, wave = tid >> 6, lane = tid & 63;
    const int fr = lane & 15, fq = lane >> 4;
    const int frx = fr & 7;
    const int q0 = qt * 64;
    const size_t hoff = ((size_t)n * NH + h) * SL * HD;
    const f32x4 z4 = {0.f, 0.f, 0.f, 0.f};

    // q fragments (persist whole kernel)
    bf16x8 qf0, qf1;
    {
        const size_t qb = hoff + (size_t)(q0 + wave * 16 + fr) * HD + fq * 8;
        qf0 = *(const bf16x8*)(qh + qb);
        qf1 = *(const bf16x8*)(qh + qb + 32);
    }

    f32x4 o[4];
#pragma unroll
    for (int f = 0; f < 4; ++f) o[f] = z4;
    float mj[4] = {-3e38f, -3e38f, -3e38f, -3e38f};
    float sj[4] = {0.f, 0.f, 0.f, 0.f};
    size_t brow[4];
#pragma unroll
    for (int j = 0; j < 4; ++j)
        brow[j] = ((size_t)h * SL + q0 + wave * 16 + fq * 4 + j) * SL;
    const int* mkb = mask + n * SL;

    // V write helper target rows: d0 = wave*8 (part0), d1 = (wave+4)*8 (part1)
    // ---- prologue ----
#pragma unroll
    for (int i = 0; i < 2; ++i) {
        const int li = i * 256 + tid;
        const int r = li >> 3, s = li & 7;
        gl_lds16(kh + hoff + (size_t)r * HD + (s ^ (r & 7)) * 8,
                 &Ks[0][(i * 256 + wave * 64) * 8]);
    }
    // V(0) -> regs -> Vs[0] (transposed, swizzled write), BOTH d-halves
    bf16x8 vr0 = *(const bf16x8*)(vh + hoff + (size_t)lane * HD + wave * 8);
    bf16x8 vr1 = *(const bf16x8*)(vh + hoff + (size_t)lane * HD + (wave + 4) * 8);
#pragma unroll
    for (int e = 0; e < 8; ++e) {
        const int d0 = wave * 8 + e, d1 = (wave + 4) * 8 + e;
        Vs[0][d0 * 64 + (((lane >> 3) ^ (d0 & 7)) << 3) + (lane & 7)] = vr0[e];
        Vs[0][d1 * 64 + (((lane >> 3) ^ (d1 & 7)) << 3) + (lane & 7)] = vr1[e];
    }
    // V(1) -> regs
    vr0 = *(const bf16x8*)(vh + hoff + (size_t)(64 + lane) * HD + wave * 8);
    vr1 = *(const bf16x8*)(vh + hoff + (size_t)(64 + lane) * HD + (wave + 4) * 8);
    // bias(0)/mask(0) -> regs
    float bc[4][4];
    int mkc[4];
#pragma unroll
    for (int nf = 0; nf < 4; ++nf) {
        mkc[nf] = mkb[nf * 16 + fr];
#pragma unroll
        for (int j = 0; j < 4; ++j)
            bc[nf][j] = bias[brow[j] + nf * 16 + fr];
    }
    __syncthreads();

    int cur = 0;
#pragma unroll 1
    for (int kt = 0; kt < 32; ++kt) {
        const int nxt = cur ^ 1;
        const int kp1 = (kt < 31) ? kt + 1 : 31;
        const int kp2 = (kt < 30) ? kt + 2 : 31;

        // 1. stage K(kt+1) -> Ks[nxt]
#pragma unroll
        for (int i = 0; i < 2; ++i) {
            const int li = i * 256 + tid;
            const int r = li >> 3, s = li & 7;
            gl_lds16(kh + hoff + (size_t)(kp1 * 64 + r) * HD + (s ^ (r & 7)) * 8,
                     &Ks[nxt][(i * 256 + wave * 64) * 8]);
        }
        // 2. Vs[nxt] <- vr0/vr1 (= V(kt+1)), both d-halves
#pragma unroll
        for (int e = 0; e < 8; ++e) {
            const int d0 = wave * 8 + e, d1 = (wave + 4) * 8 + e;
            Vs[nxt][d0 * 64 + (((lane >> 3) ^ (d0 & 7)) << 3) + (lane & 7)] = vr0[e];
            Vs[nxt][d1 * 64 + (((lane >> 3) ^ (d1 & 7)) << 3) + (lane & 7)] = vr1[e];
        }
        // 3. V(kt+2) -> regs
        vr0 = *(const bf16x8*)(vh + hoff + (size_t)(kp2 * 64 + lane) * HD + wave * 8);
        vr1 = *(const bf16x8*)(vh + hoff + (size_t)(kp2 * 64 + lane) * HD + (wave + 4) * 8);
        // 4. bias(kt+1)/mask(kt+1) -> regs
        float bn[4][4];
        int mkn[4];
#pragma unroll
        for (int nf = 0; nf < 4; ++nf) {
            mkn[nf] = mkb[kp1 * 64 + nf * 16 + fr];
#pragma unroll
            for (int j = 0; j < 4; ++j)
                bn[nf][j] = bias[brow[j] + kp1 * 64 + nf * 16 + fr];
        }

        // 5. QK^T (hi-only; bit-identical chain to k_avg)
        f32x4 sf[4];
        __builtin_amdgcn_s_setprio(1);
#pragma unroll
        for (int nf = 0; nf < 4; ++nf) {
            const bf16* kp = &Ks[cur][(nf * 16 + fr) * 64];
            const bf16x8 b0 = *(const bf16x8*)&kp[(fq ^ frx) * 8];
            const bf16x8 b1 = *(const bf16x8*)&kp[((fq + 4) ^ frx) * 8];
            f32x4 a = z4;
            a = MFMA16(qf0, b0, a);
            a = MFMA16(qf1, b1, a);
            sf[nf] = a;
        }
        __builtin_amdgcn_s_setprio(0);

        // bias + mask (current tile's prefetched values)
#pragma unroll
        for (int nf = 0; nf < 4; ++nf) {
            const bool mk = mkc[nf] != 0;
#pragma unroll
            for (int j = 0; j < 4; ++j) {
                float s = sf[nf][j] + bc[nf][j];
                sf[nf][j] = mk ? -1e30f : s;
            }
        }
        // online softmax (rows wave-local; 16-lane butterfly)
        float tmax[4];
#pragma unroll
        for (int j = 0; j < 4; ++j)
            tmax[j] = fmaxf(fmaxf(sf[0][j], sf[1][j]), fmaxf(sf[2][j], sf[3][j]));
#pragma unroll
        for (int d = 1; d < 16; d <<= 1)
#pragma unroll
            for (int j = 0; j < 4; ++j)
                tmax[j] = fmaxf(tmax[j], __shfl_xor(tmax[j], d));
        float scale[4];
#pragma unroll
        for (int j = 0; j < 4; ++j) {
            const float mn = fmaxf(mj[j], tmax[j]);
            scale[j] = __expf(mj[j] - mn);
            mj[j] = mn;
        }
        float rs[4] = {0.f, 0.f, 0.f, 0.f};
#pragma unroll
        for (int nf = 0; nf < 4; ++nf)
#pragma unroll
            for (int j = 0; j < 4; ++j) {
                const float w = __expf(sf[nf][j] - mj[j]);
                sf[nf][j] = w;
                rs[j] += w;
            }
#pragma unroll
        for (int d = 1; d < 16; d <<= 1)
#pragma unroll
            for (int j = 0; j < 4; ++j)
                rs[j] += __shfl_xor(rs[j], d);
#pragma unroll
        for (int j = 0; j < 4; ++j) sj[j] = sj[j] * scale[j] + rs[j];
#pragma unroll
        for (int f = 0; f < 4; ++f)
#pragma unroll
            for (int j = 0; j < 4; ++j) o[f][j] *= scale[j];

        // P -> per-wave swizzled LDS tile
#pragma unroll
        for (int nf = 0; nf < 4; ++nf)
#pragma unroll
            for (int j = 0; j < 4; ++j) {
                const int row = fq * 4 + j, col = nf * 16 + fr;
                Ws[wave][row * 64 + (((col >> 3) ^ (row & 7)) << 3) + (fr & 7)] =
                    (bf16)sf[nf][j];
            }
        // PV
        const bf16* wp = &Ws[wave][fr * 64];
        const bf16x8 wa0 = *(const bf16x8*)&wp[(fq ^ frx) * 8];
        const bf16x8 wa1 = *(const bf16x8*)&wp[((fq + 4) ^ frx) * 8];
        __builtin_amdgcn_s_setprio(1);
#pragma unroll
        for (int f = 0; f < 4; ++f) {
            const bf16* vp = &Vs[cur][(f * 16 + fr) * 64];
            const bf16x8 vb0 = *(const bf16x8*)&vp[(fq ^ frx) * 8];
            const bf16x8 vb1 = *(const bf16x8*)&vp[((fq + 4) ^ frx) * 8];
            o[f] = MFMA16(wa0, vb0, o[f]);
            o[f] = MFMA16(wa1, vb1, o[f]);
        }
        __builtin_amdgcn_s_setprio(0);

        // rotate prefetched scalars; single barrier per tile
#pragma unroll
        for (int nf = 0; nf < 4; ++nf) {
            mkc[nf] = mkn[nf];
#pragma unroll
            for (int j = 0; j < 4; ++j) bc[nf][j] = bn[nf][j];
        }
        __syncthreads();
        cur = nxt;
    }

    // epilogue: context (hi/lo) + row stats
#pragma unroll
    for (int j = 0; j < 4; ++j) {
        const float inv = 1.0f / sj[j];
        const int row = n * SL + q0 + wave * 16 + fq * 4 + j;
#pragma unroll
        for (int f = 0; f < 4; ++f) {
            const float v = o[f][j] * inv;
            const size_t off = (size_t)row * ED + h * HD + f * 16 + fr;
            const bf16 hv = (bf16)v;
            ch[off] = hv;
            cl[off] = (bf16)(v - (float)hv);
        }
    }
    if (fr == 0) {
#pragma unroll
        for (int j = 0; j < 4; ++j) {
            const int r = q0 + wave * 16 + fq * 4 + j;
            mrow[((size_t)n * NH + h) * SL + r] = mj[j];
            srow[((size_t)n * NH + h) * SL + r] = sj[j];
        }
    }
}

// ------------------- head-averaged weights (LDS accumulator, bf16-hi scores) -------------------
__global__ __launch_bounds__(256) void k_avg(
    const bf16* __restrict__ qh, const bf16* __restrict__ kh,
    const float* __restrict__ bias, const int* __restrict__ mask,
    const float* __restrict__ mrow, const float* __restrict__ srow,
    float* __restrict__ avg)
{
    constexpr int RS = 66;                       // row stride (floats): fq bank shift = 8
    __shared__ float accS[4 * 64 * RS];          // 67.6 KB: [nn][qrow(64)][kcol(64)+pad]

    const int qt = blockIdx.x, kt = blockIdx.y;
    const int tid = threadIdx.x, wave = tid >> 6, lane = tid & 63;
    const int fr = lane & 15, fq = lane >> 4;
    const int q0 = qt * 64, k0 = kt * 64;
    const int qr = q0 + wave * 16;
    const f32x4 z4 = {0.f, 0.f, 0.f, 0.f};

    for (int i = tid; i < 4 * 64 * RS; i += 256) accS[i] = 0.f;

    bool mk[4][4];
#pragma unroll
    for (int nn = 0; nn < 4; ++nn)
#pragma unroll
        for (int nf = 0; nf < 4; ++nf)
            mk[nn][nf] = mask[nn * SL + k0 + nf * 16 + fr] != 0;
    __syncthreads();

#pragma unroll 1
    for (int h = 0; h < NH; ++h) {
        float bfr[4][4];
#pragma unroll
        for (int nf = 0; nf < 4; ++nf)
#pragma unroll
            for (int j = 0; j < 4; ++j)
                bfr[nf][j] = bias[((size_t)h * SL + qr + fq * 4 + j) * SL + k0 + nf * 16 + fr];
#pragma unroll 1
        for (int nn = 0; nn < 4; ++nn) {
            const size_t hoff = ((size_t)nn * NH + h) * SL * HD;
            const size_t qb = hoff + (size_t)(qr + fr) * HD + fq * 8;
            const bf16x8 qf0 = *(const bf16x8*)(qh + qb);
            const bf16x8 qf1 = *(const bf16x8*)(qh + qb + 32);
            float mv[4], inv[4];
#pragma unroll
            for (int j = 0; j < 4; ++j) {
                const size_t sidx = ((size_t)nn * NH + h) * SL + qr + fq * 4 + j;
                mv[j] = mrow[sidx];
                inv[j] = 1.0f / (16.0f * srow[sidx]);
            }
#pragma unroll
            for (int nf = 0; nf < 4; ++nf) {
                const size_t kb = hoff + (size_t)(k0 + nf * 16 + fr) * HD + fq * 8;
                const bf16x8 b0 = *(const bf16x8*)(kh + kb);
                const bf16x8 b1 = *(const bf16x8*)(kh + kb + 32);
                f32x4 a = z4;
                a = MFMA16(qf0, b0, a);
                a = MFMA16(qf1, b1, a);
                float* ap = &accS[((nn * 64 + wave * 16 + fq * 4) * RS) + nf * 16 + fr];
#pragma unroll
                for (int j = 0; j < 4; ++j) {
                    const float w = mk[nn][nf] ? 0.f
                        : __expf(a[j] + bfr[nf][j] - mv[j]) * inv[j];
                    ap[j * RS] += w;
                }
            }
        }
    }
    __syncthreads();

    // coalesced writeback: 16 (nn,row) pairs per pass, 16 lanes x f32x4 per row
#pragma unroll 1
    for (int p = 0; p < 16; ++p) {
        const int pair = p * 16 + (tid >> 4);
        const int nn = pair >> 6, row = pair & 63;
        const int c = (tid & 15) * 4;
        const float* src = &accS[(nn * 64 + row) * RS + c];
        f32x4 v = {src[0], src[1], src[2], src[3]};
        *(f32x4*)&avg[((size_t)nn * SL + q0 + row) * SL + k0 + c] = v;
    }
}

// ------------------- launcher -------------------
extern "C" void kernel_launch(void* const* d_in, const int* in_sizes, int n_in,
                              void* d_out, int out_size, void* d_ws, size_t ws_size,
                              hipStream_t stream)
{
    (void)in_sizes; (void)n_in; (void)out_size; (void)ws_size;
    const float* query = (const float*)d_in[0];
    const float* bias  = (const float*)d_in[1];
    const int* mask = (const int*)d_in[2];
    const float* Wq = (const float*)d_in[3];
    const float* bq = (const float*)d_in[4];
    const float* Wk = (const float*)d_in[5];
    const float* bk = (const float*)d_in[6];
    const float* Wv = (const float*)d_in[7];
    const float* bv = (const float*)d_in[8];
    const float* Wo = (const float*)d_in[9];
    const float* bo = (const float*)d_in[10];
    float* out0 = (float*)d_out;                      // [N,L,E]
    float* out1 = out0 + (size_t)MR * ED;             // [N,L,L]

    char* p = (char*)d_ws;
    auto carve = [&](size_t bytes) {
        char* r = p;
        p += (bytes + 255) & ~(size_t)255;
        return r;
    };
    const size_t QKVB = (size_t)NB * NH * SL * HD * 2;   // 16.78 MB
    bf16* xh = (bf16*)carve((size_t)MR * ED * 2);
    bf16* xl = (bf16*)carve((size_t)MR * ED * 2);
    bf16* wh = (bf16*)carve((size_t)4 * ED * ED * 2);
    bf16* wl = (bf16*)carve((size_t)4 * ED * ED * 2);
    bf16* qh = (bf16*)carve(QKVB);
    bf16* kh = (bf16*)carve(QKVB);
    bf16* vh = (bf16*)carve(QKVB);
    float* mrow = (float*)carve((size_t)NB * NH * SL * 4);
    float* srow = (float*)carve((size_t)NB * NH * SL * 4);
    bf16* ch = (bf16*)carve((size_t)MR * ED * 2);
    bf16* cl = (bf16*)carve((size_t)MR * ED * 2);

    // 1. split inputs to hi/lo bf16
    {
        const int n4 = MR * ED / 4;
        k_split<<<(n4 + 255) / 256, 256, 0, stream>>>(query, xh, xl, n4);
        const int w4 = ED * ED / 4;
        const float* Ws4[4] = {Wq, Wk, Wv, Wo};
        for (int i = 0; i < 4; ++i)
            k_split<<<(w4 + 255) / 256, 256, 0, stream>>>(
                Ws4[i], wh + (size_t)i * ED * ED, wl + (size_t)i * ED * ED, w4);
    }
    // 2. QKV projections
    k_qkv_gemm<<<dim3(MR / 128, ED / 128, 3), 256, 0, stream>>>(
        xh, xl, wh, wl, bq, bk, bv, qh, kh, vh);
    // 3. flash attention + row stats + context
    k_flash<<<dim3(2048), 256, 0, stream>>>(
        qh, kh, vh, bias, mask, ch, cl, mrow, srow);
    // 4. head-averaged attention weights
    k_avg<<<dim3(SL / 64, SL / 64), 256, 0, stream>>>(
        qh, kh, bias, mask, mrow, srow, out1);
    // 5. output projection
    k_out_gemm<<<dim3(MR / 128, ED / 128), 256, 0, stream>>>(
        ch, cl, wh + (size_t)3 * ED * ED, wl + (size_t)3 * ED * ED, bo, out0);
}

// Round 6
// 957.077 us; speedup vs baseline: 2.3378x; 1.0111x over previous
//
#include <hip/hip_runtime.h>
#include <stdint.h>

typedef __bf16 bf16;
typedef __bf16 bf16x4 __attribute__((ext_vector_type(4)));
typedef __bf16 bf16x8 __attribute__((ext_vector_type(8)));
typedef float f32x4 __attribute__((ext_vector_type(4)));

#define MFMA16(a, b, c) __builtin_amdgcn_mfma_f32_16x16x32_bf16((a), (b), (c), 0, 0, 0)

static constexpr int NB = 4;      // batch
static constexpr int NH = 16;     // heads
static constexpr int SL = 2048;   // seq len
static constexpr int HD = 64;     // head dim
static constexpr int ED = 1024;   // embed
static constexpr int MR = NB * SL; // 8192 rows

__device__ __forceinline__ void gl_lds16(const void* g, void* l) {
    __builtin_amdgcn_global_load_lds(
        (const __attribute__((address_space(1))) unsigned int*)g,
        (__attribute__((address_space(3))) unsigned int*)l, 16, 0, 0);
}

// ------------------- f32 -> bf16 hi/lo split -------------------
__global__ void k_split(const float* __restrict__ src, bf16* __restrict__ hi,
                        bf16* __restrict__ lo, int n4) {
    int i = blockIdx.x * blockDim.x + threadIdx.x;
    if (i >= n4) return;
    const float4 v = ((const float4*)src)[i];
    float vv[4] = {v.x, v.y, v.z, v.w};
    bf16x4 hv, lv;
#pragma unroll
    for (int e = 0; e < 4; ++e) {
        bf16 h = (bf16)vv[e];
        hv[e] = h;
        lv[e] = (bf16)(vv[e] - (float)h);
    }
    ((bf16x4*)hi)[i] = hv;
    ((bf16x4*)lo)[i] = lv;
}

// ------------------- QKV projection GEMM (hi/lo inputs, bf16 outputs) -------------------
__global__ __launch_bounds__(256) void k_qkv_gemm(
    const bf16* __restrict__ xh, const bf16* __restrict__ xl,
    const bf16* __restrict__ wh, const bf16* __restrict__ wl,
    const float* __restrict__ bq, const float* __restrict__ bk,
    const float* __restrict__ bv,
    bf16* __restrict__ qh, bf16* __restrict__ kh, bf16* __restrict__ vh)
{
    __shared__ __attribute__((aligned(16))) bf16 As[2][128 * 32];
    __shared__ __attribute__((aligned(16))) bf16 Bs[2][128 * 32];

    const int z  = blockIdx.z;           // 0=q,1=k,2=v
    const int m0 = blockIdx.x * 128;
    const int n0 = blockIdx.y * 128;
    const int tid = threadIdx.x, wave = tid >> 6, lane = tid & 63;
    const int wr = wave >> 1, wc = wave & 1;
    const int fr = lane & 15, fq = lane >> 4;
    const bf16* Wh = wh + (size_t)z * ED * ED;
    const bf16* Wl = wl + (size_t)z * ED * ED;

    const f32x4 z4 = {0.f, 0.f, 0.f, 0.f};
    f32x4 acc[4][4];
#pragma unroll
    for (int i = 0; i < 4; ++i)
#pragma unroll
        for (int j = 0; j < 4; ++j) acc[i][j] = z4;

#pragma unroll 1
    for (int kk = 0; kk < ED; kk += 32) {
#pragma unroll
        for (int r = 0; r < 2; ++r) {
            const int chunk = r * 256 + tid;
            const int row = chunk >> 2, c8 = (chunk & 3) * 8;
            const size_t ax = (size_t)(m0 + row) * ED + kk + c8;
            const size_t bx = (size_t)(n0 + row) * ED + kk + c8;
            const int db = (r * 256 + wave * 64) * 8;   // wave-uniform LDS base
            gl_lds16(xh + ax, &As[0][db]);
            gl_lds16(xl + ax, &As[1][db]);
            gl_lds16(Wh + bx, &Bs[0][db]);
            gl_lds16(Wl + bx, &Bs[1][db]);
        }
        __syncthreads();
        bf16x8 af[4][2], bfg[4][2];
#pragma unroll
        for (int i = 0; i < 4; ++i) {
            const int arow = wr * 64 + i * 16 + fr;
            af[i][0] = *(const bf16x8*)&As[0][arow * 32 + fq * 8];
            af[i][1] = *(const bf16x8*)&As[1][arow * 32 + fq * 8];
            const int brow = wc * 64 + i * 16 + fr;
            bfg[i][0] = *(const bf16x8*)&Bs[0][brow * 32 + fq * 8];
            bfg[i][1] = *(const bf16x8*)&Bs[1][brow * 32 + fq * 8];
        }
#pragma unroll
        for (int mi = 0; mi < 4; ++mi)
#pragma unroll
            for (int ni = 0; ni < 4; ++ni) {
                acc[mi][ni] = MFMA16(af[mi][0], bfg[ni][0], acc[mi][ni]);
                acc[mi][ni] = MFMA16(af[mi][0], bfg[ni][1], acc[mi][ni]);
                acc[mi][ni] = MFMA16(af[mi][1], bfg[ni][0], acc[mi][ni]);
            }
        __syncthreads();
    }

    const float* bias = (z == 0) ? bq : (z == 1) ? bk : bv;
#pragma unroll
    for (int mi = 0; mi < 4; ++mi) {
#pragma unroll
        for (int ni = 0; ni < 4; ++ni) {
            const int col = n0 + wc * 64 + ni * 16 + fr;
            const int hh = col >> 6, dd = col & 63;
#pragma unroll
            for (int j = 0; j < 4; ++j) {
                const int row = m0 + wr * 64 + mi * 16 + fq * 4 + j;
                float v = acc[mi][ni][j] + bias[col];
                const int nb = row >> 11, li = row & (SL - 1);
                const size_t off = (((size_t)nb * NH + hh) * SL + li) * HD + dd;
                if (z == 0) {
                    qh[off] = (bf16)(v * 0.125f);      // head_dim^-0.5
                } else if (z == 1) {
                    kh[off] = (bf16)v;
                } else {
                    vh[off] = (bf16)v;
                }
            }
        }
    }
}

// ------------------- output projection GEMM (hi/lo) -------------------
__global__ __launch_bounds__(256) void k_out_gemm(
    const bf16* __restrict__ ah, const bf16* __restrict__ al,
    const bf16* __restrict__ wh, const bf16* __restrict__ wl,
    const float* __restrict__ bo, float* __restrict__ out)
{
    __shared__ __attribute__((aligned(16))) bf16 As[2][128 * 32];
    __shared__ __attribute__((aligned(16))) bf16 Bs[2][128 * 32];

    const int m0 = blockIdx.x * 128;
    const int n0 = blockIdx.y * 128;
    const int tid = threadIdx.x, wave = tid >> 6, lane = tid & 63;
    const int wr = wave >> 1, wc = wave & 1;
    const int fr = lane & 15, fq = lane >> 4;

    const f32x4 z4 = {0.f, 0.f, 0.f, 0.f};
    f32x4 acc[4][4];
#pragma unroll
    for (int i = 0; i < 4; ++i)
#pragma unroll
        for (int j = 0; j < 4; ++j) acc[i][j] = z4;

#pragma unroll 1
    for (int kk = 0; kk < ED; kk += 32) {
#pragma unroll
        for (int r = 0; r < 2; ++r) {
            const int chunk = r * 256 + tid;
            const int row = chunk >> 2, c8 = (chunk & 3) * 8;
            const size_t ax = (size_t)(m0 + row) * ED + kk + c8;
            const size_t bx = (size_t)(n0 + row) * ED + kk + c8;
            const int db = (r * 256 + wave * 64) * 8;
            gl_lds16(ah + ax, &As[0][db]);
            gl_lds16(al + ax, &As[1][db]);
            gl_lds16(wh + bx, &Bs[0][db]);
            gl_lds16(wl + bx, &Bs[1][db]);
        }
        __syncthreads();
        bf16x8 af[4][2], bfg[4][2];
#pragma unroll
        for (int i = 0; i < 4; ++i) {
            const int arow = wr * 64 + i * 16 + fr;
            af[i][0] = *(const bf16x8*)&As[0][arow * 32 + fq * 8];
            af[i][1] = *(const bf16x8*)&As[1][arow * 32 + fq * 8];
            const int brow = wc * 64 + i * 16 + fr;
            bfg[i][0] = *(const bf16x8*)&Bs[0][brow * 32 + fq * 8];
            bfg[i][1] = *(const bf16x8*)&Bs[1][brow * 32 + fq * 8];
        }
#pragma unroll
        for (int mi = 0; mi < 4; ++mi)
#pragma unroll
            for (int ni = 0; ni < 4; ++ni) {
                acc[mi][ni] = MFMA16(af[mi][0], bfg[ni][0], acc[mi][ni]);
                acc[mi][ni] = MFMA16(af[mi][0], bfg[ni][1], acc[mi][ni]);
                acc[mi][ni] = MFMA16(af[mi][1], bfg[ni][0], acc[mi][ni]);
            }
        __syncthreads();
    }

#pragma unroll
    for (int mi = 0; mi < 4; ++mi)
#pragma unroll
        for (int ni = 0; ni < 4; ++ni) {
            const int col = n0 + wc * 64 + ni * 16 + fr;
#pragma unroll
            for (int j = 0; j < 4; ++j) {
                const int row = m0 + wr * 64 + mi * 16 + fq * 4 + j;
                out[(size_t)row * ED + col] = acc[mi][ni][j] + bo[col];
            }
        }
}

// ------------------- flash attention v2.1 -------------------
// One block per (n,h,64-row q-tile). K staged via global_load_lds (linear dest,
// inverse-swizzled source); V transposed + P tile written at XOR-swizzled slots
// (chunk ^= row&7 within 128B rows). Depth-1 prefetch, ONE barrier per K-tile.
__global__ __launch_bounds__(256) void k_flash(
    const bf16* __restrict__ qh, const bf16* __restrict__ kh,
    const bf16* __restrict__ vh,
    const float* __restrict__ bias, const int* __restrict__ mask,
    bf16* __restrict__ ch, bf16* __restrict__ cl,
    float* __restrict__ mrow, float* __restrict__ srow)
{
    __shared__ __attribute__((aligned(16))) bf16 Ks[2][64 * 64];  // [key][d] swz
    __shared__ __attribute__((aligned(16))) bf16 Vs[2][64 * 64];  // [d][key] swz
    __shared__ __attribute__((aligned(16))) bf16 Ws[4][16 * 64];  // per-wave P, swz

    // XCD-chunked swizzle: each XCD gets 256 consecutive wg = 8 full (n,h) groups
    const int bid = blockIdx.x;
    const int wg = (bid & 7) * 256 + (bid >> 3);
    const int qt = wg & 31, h = (wg >> 5) & 15, n = wg >> 9;

    const int tid = threadIdx.x, wave = tid >> 6, lane = tid & 63;
    const int fr = lane & 15, fq = lane >> 4;
    const int frx = fr & 7;
    const int q0 = qt * 64;
    const size_t hoff = ((size_t)n * NH + h) * SL * HD;
    const f32x4 z4 = {0.f, 0.f, 0.f, 0.f};

    // q fragments (persist whole kernel)
    bf16x8 qf0, qf1;
    {
        const size_t qb = hoff + (size_t)(q0 + wave * 16 + fr) * HD + fq * 8;
        qf0 = *(const bf16x8*)(qh + qb);
        qf1 = *(const bf16x8*)(qh + qb + 32);
    }

    f32x4 o[4];
#pragma unroll
    for (int f = 0; f < 4; ++f) o[f] = z4;
    float mj[4] = {-3e38f, -3e38f, -3e38f, -3e38f};
    float sj[4] = {0.f, 0.f, 0.f, 0.f};
    size_t brow[4];
#pragma unroll
    for (int j = 0; j < 4; ++j)
        brow[j] = ((size_t)h * SL + q0 + wave * 16 + fq * 4 + j) * SL;
    const int* mkb = mask + n * SL;

    // ---- prologue ----
#pragma unroll
    for (int i = 0; i < 2; ++i) {
        const int li = i * 256 + tid;
        const int r = li >> 3, s = li & 7;
        gl_lds16(kh + hoff + (size_t)r * HD + (s ^ (r & 7)) * 8,
                 &Ks[0][(i * 256 + wave * 64) * 8]);
    }
    // V(0) -> regs -> Vs[0] (transposed, swizzled write), BOTH d-halves
    bf16x8 vr0 = *(const bf16x8*)(vh + hoff + (size_t)lane * HD + wave * 8);
    bf16x8 vr1 = *(const bf16x8*)(vh + hoff + (size_t)lane * HD + (wave + 4) * 8);
#pragma unroll
    for (int e = 0; e < 8; ++e) {
        const int d0 = wave * 8 + e, d1 = (wave + 4) * 8 + e;
        Vs[0][d0 * 64 + (((lane >> 3) ^ (d0 & 7)) << 3) + (lane & 7)] = vr0[e];
        Vs[0][d1 * 64 + (((lane >> 3) ^ (d1 & 7)) << 3) + (lane & 7)] = vr1[e];
    }
    // V(1) -> regs
    vr0 = *(const bf16x8*)(vh + hoff + (size_t)(64 + lane) * HD + wave * 8);
    vr1 = *(const bf16x8*)(vh + hoff + (size_t)(64 + lane) * HD + (wave + 4) * 8);
    // bias(0)/mask(0) -> regs
    float bc[4][4];
    int mkc[4];
#pragma unroll
    for (int nf = 0; nf < 4; ++nf) {
        mkc[nf] = mkb[nf * 16 + fr];
#pragma unroll
        for (int j = 0; j < 4; ++j)
            bc[nf][j] = bias[brow[j] + nf * 16 + fr];
    }
    __syncthreads();

    int cur = 0;
#pragma unroll 1
    for (int kt = 0; kt < 32; ++kt) {
        const int nxt = cur ^ 1;
        const int kp1 = (kt < 31) ? kt + 1 : 31;
        const int kp2 = (kt < 30) ? kt + 2 : 31;

        // 1. stage K(kt+1) -> Ks[nxt]
#pragma unroll
        for (int i = 0; i < 2; ++i) {
            const int li = i * 256 + tid;
            const int r = li >> 3, s = li & 7;
            gl_lds16(kh + hoff + (size_t)(kp1 * 64 + r) * HD + (s ^ (r & 7)) * 8,
                     &Ks[nxt][(i * 256 + wave * 64) * 8]);
        }
        // 2. Vs[nxt] <- vr0/vr1 (= V(kt+1)), both d-halves
#pragma unroll
        for (int e = 0; e < 8; ++e) {
            const int d0 = wave * 8 + e, d1 = (wave + 4) * 8 + e;
            Vs[nxt][d0 * 64 + (((lane >> 3) ^ (d0 & 7)) << 3) + (lane & 7)] = vr0[e];
            Vs[nxt][d1 * 64 + (((lane >> 3) ^ (d1 & 7)) << 3) + (lane & 7)] = vr1[e];
        }
        // 3. V(kt+2) -> regs
        vr0 = *(const bf16x8*)(vh + hoff + (size_t)(kp2 * 64 + lane) * HD + wave * 8);
        vr1 = *(const bf16x8*)(vh + hoff + (size_t)(kp2 * 64 + lane) * HD + (wave + 4) * 8);
        // 4. bias(kt+1)/mask(kt+1) -> regs
        float bn[4][4];
        int mkn[4];
#pragma unroll
        for (int nf = 0; nf < 4; ++nf) {
            mkn[nf] = mkb[kp1 * 64 + nf * 16 + fr];
#pragma unroll
            for (int j = 0; j < 4; ++j)
                bn[nf][j] = bias[brow[j] + kp1 * 64 + nf * 16 + fr];
        }

        // 5. QK^T (hi-only; bit-identical chain to k_avg)
        f32x4 sf[4];
        __builtin_amdgcn_s_setprio(1);
#pragma unroll
        for (int nf = 0; nf < 4; ++nf) {
            const bf16* kp = &Ks[cur][(nf * 16 + fr) * 64];
            const bf16x8 b0 = *(const bf16x8*)&kp[(fq ^ frx) * 8];
            const bf16x8 b1 = *(const bf16x8*)&kp[((fq + 4) ^ frx) * 8];
            f32x4 a = z4;
            a = MFMA16(qf0, b0, a);
            a = MFMA16(qf1, b1, a);
            sf[nf] = a;
        }
        __builtin_amdgcn_s_setprio(0);

        // bias + mask (current tile's prefetched values)
#pragma unroll
        for (int nf = 0; nf < 4; ++nf) {
            const bool mk = mkc[nf] != 0;
#pragma unroll
            for (int j = 0; j < 4; ++j) {
                float s = sf[nf][j] + bc[nf][j];
                sf[nf][j] = mk ? -1e30f : s;
            }
        }
        // online softmax (rows wave-local; 16-lane butterfly)
        float tmax[4];
#pragma unroll
        for (int j = 0; j < 4; ++j)
            tmax[j] = fmaxf(fmaxf(sf[0][j], sf[1][j]), fmaxf(sf[2][j], sf[3][j]));
#pragma unroll
        for (int d = 1; d < 16; d <<= 1)
#pragma unroll
            for (int j = 0; j < 4; ++j)
                tmax[j] = fmaxf(tmax[j], __shfl_xor(tmax[j], d));
        float scale[4];
#pragma unroll
        for (int j = 0; j < 4; ++j) {
            const float mn = fmaxf(mj[j], tmax[j]);
            scale[j] = __expf(mj[j] - mn);
            mj[j] = mn;
        }
        float rs[4] = {0.f, 0.f, 0.f, 0.f};
#pragma unroll
        for (int nf = 0; nf < 4; ++nf)
#pragma unroll
            for (int j = 0; j < 4; ++j) {
                const float w = __expf(sf[nf][j] - mj[j]);
                sf[nf][j] = w;
                rs[j] += w;
            }
#pragma unroll
        for (int d = 1; d < 16; d <<= 1)
#pragma unroll
            for (int j = 0; j < 4; ++j)
                rs[j] += __shfl_xor(rs[j], d);
#pragma unroll
        for (int j = 0; j < 4; ++j) sj[j] = sj[j] * scale[j] + rs[j];
#pragma unroll
        for (int f = 0; f < 4; ++f)
#pragma unroll
            for (int j = 0; j < 4; ++j) o[f][j] *= scale[j];

        // P -> per-wave swizzled LDS tile
#pragma unroll
        for (int nf = 0; nf < 4; ++nf)
#pragma unroll
            for (int j = 0; j < 4; ++j) {
                const int row = fq * 4 + j, col = nf * 16 + fr;
                Ws[wave][row * 64 + (((col >> 3) ^ (row & 7)) << 3) + (fr & 7)] =
                    (bf16)sf[nf][j];
            }
        // PV
        const bf16* wp = &Ws[wave][fr * 64];
        const bf16x8 wa0 = *(const bf16x8*)&wp[(fq ^ frx) * 8];
        const bf16x8 wa1 = *(const bf16x8*)&wp[((fq + 4) ^ frx) * 8];
        __builtin_amdgcn_s_setprio(1);
#pragma unroll
        for (int f = 0; f < 4; ++f) {
            const bf16* vp = &Vs[cur][(f * 16 + fr) * 64];
            const bf16x8 vb0 = *(const bf16x8*)&vp[(fq ^ frx) * 8];
            const bf16x8 vb1 = *(const bf16x8*)&vp[((fq + 4) ^ frx) * 8];
            o[f] = MFMA16(wa0, vb0, o[f]);
            o[f] = MFMA16(wa1, vb1, o[f]);
        }
        __builtin_amdgcn_s_setprio(0);

        // rotate prefetched scalars; single barrier per tile
#pragma unroll
        for (int nf = 0; nf < 4; ++nf) {
            mkc[nf] = mkn[nf];
#pragma unroll
            for (int j = 0; j < 4; ++j) bc[nf][j] = bn[nf][j];
        }
        __syncthreads();
        cur = nxt;
    }

    // epilogue: context (hi/lo) + row stats
#pragma unroll
    for (int j = 0; j < 4; ++j) {
        const float inv = 1.0f / sj[j];
        const int row = n * SL + q0 + wave * 16 + fq * 4 + j;
#pragma unroll
        for (int f = 0; f < 4; ++f) {
            const float v = o[f][j] * inv;
            const size_t off = (size_t)row * ED + h * HD + f * 16 + fr;
            const bf16 hv = (bf16)v;
            ch[off] = hv;
            cl[off] = (bf16)(v - (float)hv);
        }
    }
    if (fr == 0) {
#pragma unroll
        for (int j = 0; j < 4; ++j) {
            const int r = q0 + wave * 16 + fq * 4 + j;
            mrow[((size_t)n * NH + h) * SL + r] = mj[j];
            srow[((size_t)n * NH + h) * SL + r] = sj[j];
        }
    }
}

// ------------------- head-averaged weights (REGISTER accumulator, nn fully unrolled) -------------------
__global__ __launch_bounds__(256) void k_avg(
    const bf16* __restrict__ qh, const bf16* __restrict__ kh,
    const float* __restrict__ bias, const int* __restrict__ mask,
    const float* __restrict__ mrow, const float* __restrict__ srow,
    float* __restrict__ avg)
{
    const int qt = blockIdx.x, kt = blockIdx.y;
    const int tid = threadIdx.x, wave = tid >> 6, lane = tid & 63;
    const int fr = lane & 15, fq = lane >> 4;
    const int q0 = qt * 64, k0 = kt * 64;
    const int qr = q0 + wave * 16;
    const f32x4 z4 = {0.f, 0.f, 0.f, 0.f};

    // acc[nn][nf] -- ALL indices compile-time constant (rule #20): stays in VGPRs
    f32x4 acc[4][4];
#pragma unroll
    for (int nn = 0; nn < 4; ++nn)
#pragma unroll
        for (int nf = 0; nf < 4; ++nf) acc[nn][nf] = z4;

    bool mk[4][4];
#pragma unroll
    for (int nn = 0; nn < 4; ++nn)
#pragma unroll
        for (int nf = 0; nf < 4; ++nf)
            mk[nn][nf] = mask[nn * SL + k0 + nf * 16 + fr] != 0;

#pragma unroll 1
    for (int h = 0; h < NH; ++h) {
        float bfr[4][4];
#pragma unroll
        for (int nf = 0; nf < 4; ++nf)
#pragma unroll
            for (int j = 0; j < 4; ++j)
                bfr[nf][j] = bias[((size_t)h * SL + qr + fq * 4 + j) * SL + k0 + nf * 16 + fr];
#pragma unroll
        for (int nn = 0; nn < 4; ++nn) {
            const size_t hoff = ((size_t)nn * NH + h) * SL * HD;
            const size_t qb = hoff + (size_t)(qr + fr) * HD + fq * 8;
            const bf16x8 qf0 = *(const bf16x8*)(qh + qb);
            const bf16x8 qf1 = *(const bf16x8*)(qh + qb + 32);
            float mv[4], inv[4];
#pragma unroll
            for (int j = 0; j < 4; ++j) {
                const size_t sidx = ((size_t)nn * NH + h) * SL + qr + fq * 4 + j;
                mv[j] = mrow[sidx];
                inv[j] = 1.0f / (16.0f * srow[sidx]);
            }
#pragma unroll
            for (int nf = 0; nf < 4; ++nf) {
                const size_t kb = hoff + (size_t)(k0 + nf * 16 + fr) * HD + fq * 8;
                const bf16x8 b0 = *(const bf16x8*)(kh + kb);
                const bf16x8 b1 = *(const bf16x8*)(kh + kb + 32);
                f32x4 a = z4;
                a = MFMA16(qf0, b0, a);
                a = MFMA16(qf1, b1, a);
#pragma unroll
                for (int j = 0; j < 4; ++j) {
                    const float w = mk[nn][nf] ? 0.f
                        : __expf(a[j] + bfr[nf][j] - mv[j]) * inv[j];
                    acc[nn][nf][j] += w;
                }
            }
        }
    }

    // writeback: 16 lanes x 4B contiguous per (nn,nf,j) row segment
#pragma unroll
    for (int nn = 0; nn < 4; ++nn)
#pragma unroll
        for (int j = 0; j < 4; ++j) {
            const size_t rowoff = ((size_t)nn * SL + qr + fq * 4 + j) * SL;
#pragma unroll
            for (int nf = 0; nf < 4; ++nf)
                avg[rowoff + k0 + nf * 16 + fr] = acc[nn][nf][j];
        }
}

// ------------------- launcher -------------------
extern "C" void kernel_launch(void* const* d_in, const int* in_sizes, int n_in,
                              void* d_out, int out_size, void* d_ws, size_t ws_size,
                              hipStream_t stream)
{
    (void)in_sizes; (void)n_in; (void)out_size; (void)ws_size;
    const float* query = (const float*)d_in[0];
    const float* bias  = (const float*)d_in[1];
    const int* mask = (const int*)d_in[2];
    const float* Wq = (const float*)d_in[3];
    const float* bq = (const float*)d_in[4];
    const float* Wk = (const float*)d_in[5];
    const float* bk = (const float*)d_in[6];
    const float* Wv = (const float*)d_in[7];
    const float* bv = (const float*)d_in[8];
    const float* Wo = (const float*)d_in[9];
    const float* bo = (const float*)d_in[10];
    float* out0 = (float*)d_out;                      // [N,L,E]
    float* out1 = out0 + (size_t)MR * ED;             // [N,L,L]

    char* p = (char*)d_ws;
    auto carve = [&](size_t bytes) {
        char* r = p;
        p += (bytes + 255) & ~(size_t)255;
        return r;
    };
    const size_t QKVB = (size_t)NB * NH * SL * HD * 2;   // 16.78 MB
    bf16* xh = (bf16*)carve((size_t)MR * ED * 2);
    bf16* xl = (bf16*)carve((size_t)MR * ED * 2);
    bf16* wh = (bf16*)carve((size_t)4 * ED * ED * 2);
    bf16* wl = (bf16*)carve((size_t)4 * ED * ED * 2);
    bf16* qh = (bf16*)carve(QKVB);
    bf16* kh = (bf16*)carve(QKVB);
    bf16* vh = (bf16*)carve(QKVB);
    float* mrow = (float*)carve((size_t)NB * NH * SL * 4);
    float* srow = (float*)carve((size_t)NB * NH * SL * 4);
    bf16* ch = (bf16*)carve((size_t)MR * ED * 2);
    bf16* cl = (bf16*)carve((size_t)MR * ED * 2);

    // 1. split inputs to hi/lo bf16
    {
        const int n4 = MR * ED / 4;
        k_split<<<(n4 + 255) / 256, 256, 0, stream>>>(query, xh, xl, n4);
        const int w4 = ED * ED / 4;
        const float* Ws4[4] = {Wq, Wk, Wv, Wo};
        for (int i = 0; i < 4; ++i)
            k_split<<<(w4 + 255) / 256, 256, 0, stream>>>(
                Ws4[i], wh + (size_t)i * ED * ED, wl + (size_t)i * ED * ED, w4);
    }
    // 2. QKV projections
    k_qkv_gemm<<<dim3(MR / 128, ED / 128, 3), 256, 0, stream>>>(
        xh, xl, wh, wl, bq, bk, bv, qh, kh, vh);
    // 3. flash attention + row stats + context
    k_flash<<<dim3(2048), 256, 0, stream>>>(
        qh, kh, vh, bias, mask, ch, cl, mrow, srow);
    // 4. head-averaged attention weights
    k_avg<<<dim3(SL / 64, SL / 64), 256, 0, stream>>>(
        qh, kh, bias, mask, mrow, srow, out1);
    // 5. output projection
    k_out_gemm<<<dim3(MR / 128, ED / 128), 256, 0, stream>>>(
        ch, cl, wh + (size_t)3 * ED * ED, wl + (size_t)3 * ED * ED, bo, out0);
}

// Round 7
// 789.793 us; speedup vs baseline: 2.8330x; 1.2118x over previous
//
#include <hip/hip_runtime.h>
#include <stdint.h>

typedef __bf16 bf16;
typedef __bf16 bf16x4 __attribute__((ext_vector_type(4)));
typedef __bf16 bf16x8 __attribute__((ext_vector_type(8)));
typedef float f32x4 __attribute__((ext_vector_type(4)));

#define MFMA16(a, b, c) __builtin_amdgcn_mfma_f32_16x16x32_bf16((a), (b), (c), 0, 0, 0)

static constexpr int NB = 4;      // batch
static constexpr int NH = 16;     // heads
static constexpr int SL = 2048;   // seq len
static constexpr int HD = 64;     // head dim
static constexpr int ED = 1024;   // embed
static constexpr int MR = NB * SL; // 8192 rows

__device__ __forceinline__ void gl_lds16(const void* g, void* l) {
    __builtin_amdgcn_global_load_lds(
        (const __attribute__((address_space(1))) unsigned int*)g,
        (__attribute__((address_space(3))) unsigned int*)l, 16, 0, 0);
}

// ------------------- f32 -> bf16 hi/lo split -------------------
__global__ void k_split(const float* __restrict__ src, bf16* __restrict__ hi,
                        bf16* __restrict__ lo, int n4) {
    int i = blockIdx.x * blockDim.x + threadIdx.x;
    if (i >= n4) return;
    const float4 v = ((const float4*)src)[i];
    float vv[4] = {v.x, v.y, v.z, v.w};
    bf16x4 hv, lv;
#pragma unroll
    for (int e = 0; e < 4; ++e) {
        bf16 h = (bf16)vv[e];
        hv[e] = h;
        lv[e] = (bf16)(vv[e] - (float)h);
    }
    ((bf16x4*)hi)[i] = hv;
    ((bf16x4*)lo)[i] = lv;
}

// ------------------- QKV projection GEMM (hi/lo inputs, bf16 outputs) -------------------
__global__ __launch_bounds__(256) void k_qkv_gemm(
    const bf16* __restrict__ xh, const bf16* __restrict__ xl,
    const bf16* __restrict__ wh, const bf16* __restrict__ wl,
    const float* __restrict__ bq, const float* __restrict__ bk,
    const float* __restrict__ bv,
    bf16* __restrict__ qh, bf16* __restrict__ kh, bf16* __restrict__ vh)
{
    __shared__ __attribute__((aligned(16))) bf16 As[2][128 * 32];
    __shared__ __attribute__((aligned(16))) bf16 Bs[2][128 * 32];

    const int z  = blockIdx.z;           // 0=q,1=k,2=v
    const int m0 = blockIdx.x * 128;
    const int n0 = blockIdx.y * 128;
    const int tid = threadIdx.x, wave = tid >> 6, lane = tid & 63;
    const int wr = wave >> 1, wc = wave & 1;
    const int fr = lane & 15, fq = lane >> 4;
    const bf16* Wh = wh + (size_t)z * ED * ED;
    const bf16* Wl = wl + (size_t)z * ED * ED;

    const f32x4 z4 = {0.f, 0.f, 0.f, 0.f};
    f32x4 acc[4][4];
#pragma unroll
    for (int i = 0; i < 4; ++i)
#pragma unroll
        for (int j = 0; j < 4; ++j) acc[i][j] = z4;

#pragma unroll 1
    for (int kk = 0; kk < ED; kk += 32) {
#pragma unroll
        for (int r = 0; r < 2; ++r) {
            const int chunk = r * 256 + tid;
            const int row = chunk >> 2, c8 = (chunk & 3) * 8;
            const size_t ax = (size_t)(m0 + row) * ED + kk + c8;
            const size_t bx = (size_t)(n0 + row) * ED + kk + c8;
            const int db = (r * 256 + wave * 64) * 8;   // wave-uniform LDS base
            gl_lds16(xh + ax, &As[0][db]);
            gl_lds16(xl + ax, &As[1][db]);
            gl_lds16(Wh + bx, &Bs[0][db]);
            gl_lds16(Wl + bx, &Bs[1][db]);
        }
        __syncthreads();
        bf16x8 af[4][2], bfg[4][2];
#pragma unroll
        for (int i = 0; i < 4; ++i) {
            const int arow = wr * 64 + i * 16 + fr;
            af[i][0] = *(const bf16x8*)&As[0][arow * 32 + fq * 8];
            af[i][1] = *(const bf16x8*)&As[1][arow * 32 + fq * 8];
            const int brow = wc * 64 + i * 16 + fr;
            bfg[i][0] = *(const bf16x8*)&Bs[0][brow * 32 + fq * 8];
            bfg[i][1] = *(const bf16x8*)&Bs[1][brow * 32 + fq * 8];
        }
#pragma unroll
        for (int mi = 0; mi < 4; ++mi)
#pragma unroll
            for (int ni = 0; ni < 4; ++ni) {
                acc[mi][ni] = MFMA16(af[mi][0], bfg[ni][0], acc[mi][ni]);
                acc[mi][ni] = MFMA16(af[mi][0], bfg[ni][1], acc[mi][ni]);
                acc[mi][ni] = MFMA16(af[mi][1], bfg[ni][0], acc[mi][ni]);
            }
        __syncthreads();
    }

    const float* bias = (z == 0) ? bq : (z == 1) ? bk : bv;
#pragma unroll
    for (int mi = 0; mi < 4; ++mi) {
#pragma unroll
        for (int ni = 0; ni < 4; ++ni) {
            const int col = n0 + wc * 64 + ni * 16 + fr;
            const int hh = col >> 6, dd = col & 63;
#pragma unroll
            for (int j = 0; j < 4; ++j) {
                const int row = m0 + wr * 64 + mi * 16 + fq * 4 + j;
                float v = acc[mi][ni][j] + bias[col];
                const int nb = row >> 11, li = row & (SL - 1);
                const size_t off = (((size_t)nb * NH + hh) * SL + li) * HD + dd;
                if (z == 0) {
                    qh[off] = (bf16)(v * 0.125f);      // head_dim^-0.5
                } else if (z == 1) {
                    kh[off] = (bf16)v;
                } else {
                    vh[off] = (bf16)v;
                }
            }
        }
    }
}

// ------------------- output projection GEMM (hi/lo) -------------------
__global__ __launch_bounds__(256) void k_out_gemm(
    const bf16* __restrict__ ah, const bf16* __restrict__ al,
    const bf16* __restrict__ wh, const bf16* __restrict__ wl,
    const float* __restrict__ bo, float* __restrict__ out)
{
    __shared__ __attribute__((aligned(16))) bf16 As[2][128 * 32];
    __shared__ __attribute__((aligned(16))) bf16 Bs[2][128 * 32];

    const int m0 = blockIdx.x * 128;
    const int n0 = blockIdx.y * 128;
    const int tid = threadIdx.x, wave = tid >> 6, lane = tid & 63;
    const int wr = wave >> 1, wc = wave & 1;
    const int fr = lane & 15, fq = lane >> 4;

    const f32x4 z4 = {0.f, 0.f, 0.f, 0.f};
    f32x4 acc[4][4];
#pragma unroll
    for (int i = 0; i < 4; ++i)
#pragma unroll
        for (int j = 0; j < 4; ++j) acc[i][j] = z4;

#pragma unroll 1
    for (int kk = 0; kk < ED; kk += 32) {
#pragma unroll
        for (int r = 0; r < 2; ++r) {
            const int chunk = r * 256 + tid;
            const int row = chunk >> 2, c8 = (chunk & 3) * 8;
            const size_t ax = (size_t)(m0 + row) * ED + kk + c8;
            const size_t bx = (size_t)(n0 + row) * ED + kk + c8;
            const int db = (r * 256 + wave * 64) * 8;
            gl_lds16(ah + ax, &As[0][db]);
            gl_lds16(al + ax, &As[1][db]);
            gl_lds16(wh + bx, &Bs[0][db]);
            gl_lds16(wl + bx, &Bs[1][db]);
        }
        __syncthreads();
        bf16x8 af[4][2], bfg[4][2];
#pragma unroll
        for (int i = 0; i < 4; ++i) {
            const int arow = wr * 64 + i * 16 + fr;
            af[i][0] = *(const bf16x8*)&As[0][arow * 32 + fq * 8];
            af[i][1] = *(const bf16x8*)&As[1][arow * 32 + fq * 8];
            const int brow = wc * 64 + i * 16 + fr;
            bfg[i][0] = *(const bf16x8*)&Bs[0][brow * 32 + fq * 8];
            bfg[i][1] = *(const bf16x8*)&Bs[1][brow * 32 + fq * 8];
        }
#pragma unroll
        for (int mi = 0; mi < 4; ++mi)
#pragma unroll
            for (int ni = 0; ni < 4; ++ni) {
                acc[mi][ni] = MFMA16(af[mi][0], bfg[ni][0], acc[mi][ni]);
                acc[mi][ni] = MFMA16(af[mi][0], bfg[ni][1], acc[mi][ni]);
                acc[mi][ni] = MFMA16(af[mi][1], bfg[ni][0], acc[mi][ni]);
            }
        __syncthreads();
    }

#pragma unroll
    for (int mi = 0; mi < 4; ++mi)
#pragma unroll
        for (int ni = 0; ni < 4; ++ni) {
            const int col = n0 + wc * 64 + ni * 16 + fr;
#pragma unroll
            for (int j = 0; j < 4; ++j) {
                const int row = m0 + wr * 64 + mi * 16 + fq * 4 + j;
                out[(size_t)row * ED + col] = acc[mi][ni][j] + bo[col];
            }
        }
}

// ------------------- flash attention v2.1 (unchanged) -------------------
__global__ __launch_bounds__(256) void k_flash(
    const bf16* __restrict__ qh, const bf16* __restrict__ kh,
    const bf16* __restrict__ vh,
    const float* __restrict__ bias, const int* __restrict__ mask,
    bf16* __restrict__ ch, bf16* __restrict__ cl,
    float* __restrict__ mrow, float* __restrict__ srow)
{
    __shared__ __attribute__((aligned(16))) bf16 Ks[2][64 * 64];  // [key][d] swz
    __shared__ __attribute__((aligned(16))) bf16 Vs[2][64 * 64];  // [d][key] swz
    __shared__ __attribute__((aligned(16))) bf16 Ws[4][16 * 64];  // per-wave P, swz

    const int bid = blockIdx.x;
    const int wg = (bid & 7) * 256 + (bid >> 3);
    const int qt = wg & 31, h = (wg >> 5) & 15, n = wg >> 9;

    const int tid = threadIdx.x, wave = tid >> 6, lane = tid & 63;
    const int fr = lane & 15, fq = lane >> 4;
    const int frx = fr & 7;
    const int q0 = qt * 64;
    const size_t hoff = ((size_t)n * NH + h) * SL * HD;
    const f32x4 z4 = {0.f, 0.f, 0.f, 0.f};

    bf16x8 qf0, qf1;
    {
        const size_t qb = hoff + (size_t)(q0 + wave * 16 + fr) * HD + fq * 8;
        qf0 = *(const bf16x8*)(qh + qb);
        qf1 = *(const bf16x8*)(qh + qb + 32);
    }

    f32x4 o[4];
#pragma unroll
    for (int f = 0; f < 4; ++f) o[f] = z4;
    float mj[4] = {-3e38f, -3e38f, -3e38f, -3e38f};
    float sj[4] = {0.f, 0.f, 0.f, 0.f};
    size_t brow[4];
#pragma unroll
    for (int j = 0; j < 4; ++j)
        brow[j] = ((size_t)h * SL + q0 + wave * 16 + fq * 4 + j) * SL;
    const int* mkb = mask + n * SL;

    // ---- prologue ----
#pragma unroll
    for (int i = 0; i < 2; ++i) {
        const int li = i * 256 + tid;
        const int r = li >> 3, s = li & 7;
        gl_lds16(kh + hoff + (size_t)r * HD + (s ^ (r & 7)) * 8,
                 &Ks[0][(i * 256 + wave * 64) * 8]);
    }
    bf16x8 vr0 = *(const bf16x8*)(vh + hoff + (size_t)lane * HD + wave * 8);
    bf16x8 vr1 = *(const bf16x8*)(vh + hoff + (size_t)lane * HD + (wave + 4) * 8);
#pragma unroll
    for (int e = 0; e < 8; ++e) {
        const int d0 = wave * 8 + e, d1 = (wave + 4) * 8 + e;
        Vs[0][d0 * 64 + (((lane >> 3) ^ (d0 & 7)) << 3) + (lane & 7)] = vr0[e];
        Vs[0][d1 * 64 + (((lane >> 3) ^ (d1 & 7)) << 3) + (lane & 7)] = vr1[e];
    }
    vr0 = *(const bf16x8*)(vh + hoff + (size_t)(64 + lane) * HD + wave * 8);
    vr1 = *(const bf16x8*)(vh + hoff + (size_t)(64 + lane) * HD + (wave + 4) * 8);
    float bc[4][4];
    int mkc[4];
#pragma unroll
    for (int nf = 0; nf < 4; ++nf) {
        mkc[nf] = mkb[nf * 16 + fr];
#pragma unroll
        for (int j = 0; j < 4; ++j)
            bc[nf][j] = bias[brow[j] + nf * 16 + fr];
    }
    __syncthreads();

    int cur = 0;
#pragma unroll 1
    for (int kt = 0; kt < 32; ++kt) {
        const int nxt = cur ^ 1;
        const int kp1 = (kt < 31) ? kt + 1 : 31;
        const int kp2 = (kt < 30) ? kt + 2 : 31;

#pragma unroll
        for (int i = 0; i < 2; ++i) {
            const int li = i * 256 + tid;
            const int r = li >> 3, s = li & 7;
            gl_lds16(kh + hoff + (size_t)(kp1 * 64 + r) * HD + (s ^ (r & 7)) * 8,
                     &Ks[nxt][(i * 256 + wave * 64) * 8]);
        }
#pragma unroll
        for (int e = 0; e < 8; ++e) {
            const int d0 = wave * 8 + e, d1 = (wave + 4) * 8 + e;
            Vs[nxt][d0 * 64 + (((lane >> 3) ^ (d0 & 7)) << 3) + (lane & 7)] = vr0[e];
            Vs[nxt][d1 * 64 + (((lane >> 3) ^ (d1 & 7)) << 3) + (lane & 7)] = vr1[e];
        }
        vr0 = *(const bf16x8*)(vh + hoff + (size_t)(kp2 * 64 + lane) * HD + wave * 8);
        vr1 = *(const bf16x8*)(vh + hoff + (size_t)(kp2 * 64 + lane) * HD + (wave + 4) * 8);
        float bn[4][4];
        int mkn[4];
#pragma unroll
        for (int nf = 0; nf < 4; ++nf) {
            mkn[nf] = mkb[kp1 * 64 + nf * 16 + fr];
#pragma unroll
            for (int j = 0; j < 4; ++j)
                bn[nf][j] = bias[brow[j] + kp1 * 64 + nf * 16 + fr];
        }

        f32x4 sf[4];
        __builtin_amdgcn_s_setprio(1);
#pragma unroll
        for (int nf = 0; nf < 4; ++nf) {
            const bf16* kp = &Ks[cur][(nf * 16 + fr) * 64];
            const bf16x8 b0 = *(const bf16x8*)&kp[(fq ^ frx) * 8];
            const bf16x8 b1 = *(const bf16x8*)&kp[((fq + 4) ^ frx) * 8];
            f32x4 a = z4;
            a = MFMA16(qf0, b0, a);
            a = MFMA16(qf1, b1, a);
            sf[nf] = a;
        }
        __builtin_amdgcn_s_setprio(0);

#pragma unroll
        for (int nf = 0; nf < 4; ++nf) {
            const bool mk = mkc[nf] != 0;
#pragma unroll
            for (int j = 0; j < 4; ++j) {
                float s = sf[nf][j] + bc[nf][j];
                sf[nf][j] = mk ? -1e30f : s;
            }
        }
        float tmax[4];
#pragma unroll
        for (int j = 0; j < 4; ++j)
            tmax[j] = fmaxf(fmaxf(sf[0][j], sf[1][j]), fmaxf(sf[2][j], sf[3][j]));
#pragma unroll
        for (int d = 1; d < 16; d <<= 1)
#pragma unroll
            for (int j = 0; j < 4; ++j)
                tmax[j] = fmaxf(tmax[j], __shfl_xor(tmax[j], d));
        float scale[4];
#pragma unroll
        for (int j = 0; j < 4; ++j) {
            const float mn = fmaxf(mj[j], tmax[j]);
            scale[j] = __expf(mj[j] - mn);
            mj[j] = mn;
        }
        float rs[4] = {0.f, 0.f, 0.f, 0.f};
#pragma unroll
        for (int nf = 0; nf < 4; ++nf)
#pragma unroll
            for (int j = 0; j < 4; ++j) {
                const float w = __expf(sf[nf][j] - mj[j]);
                sf[nf][j] = w;
                rs[j] += w;
            }
#pragma unroll
        for (int d = 1; d < 16; d <<= 1)
#pragma unroll
            for (int j = 0; j < 4; ++j)
                rs[j] += __shfl_xor(rs[j], d);
#pragma unroll
        for (int j = 0; j < 4; ++j) sj[j] = sj[j] * scale[j] + rs[j];
#pragma unroll
        for (int f = 0; f < 4; ++f)
#pragma unroll
            for (int j = 0; j < 4; ++j) o[f][j] *= scale[j];

#pragma unroll
        for (int nf = 0; nf < 4; ++nf)
#pragma unroll
            for (int j = 0; j < 4; ++j) {
                const int row = fq * 4 + j, col = nf * 16 + fr;
                Ws[wave][row * 64 + (((col >> 3) ^ (row & 7)) << 3) + (fr & 7)] =
                    (bf16)sf[nf][j];
            }
        const bf16* wp = &Ws[wave][fr * 64];
        const bf16x8 wa0 = *(const bf16x8*)&wp[(fq ^ frx) * 8];
        const bf16x8 wa1 = *(const bf16x8*)&wp[((fq + 4) ^ frx) * 8];
        __builtin_amdgcn_s_setprio(1);
#pragma unroll
        for (int f = 0; f < 4; ++f) {
            const bf16* vp = &Vs[cur][(f * 16 + fr) * 64];
            const bf16x8 vb0 = *(const bf16x8*)&vp[(fq ^ frx) * 8];
            const bf16x8 vb1 = *(const bf16x8*)&vp[((fq + 4) ^ frx) * 8];
            o[f] = MFMA16(wa0, vb0, o[f]);
            o[f] = MFMA16(wa1, vb1, o[f]);
        }
        __builtin_amdgcn_s_setprio(0);

#pragma unroll
        for (int nf = 0; nf < 4; ++nf) {
            mkc[nf] = mkn[nf];
#pragma unroll
            for (int j = 0; j < 4; ++j) bc[nf][j] = bn[nf][j];
        }
        __syncthreads();
        cur = nxt;
    }

#pragma unroll
    for (int j = 0; j < 4; ++j) {
        const float inv = 1.0f / sj[j];
        const int row = n * SL + q0 + wave * 16 + fq * 4 + j;
#pragma unroll
        for (int f = 0; f < 4; ++f) {
            const float v = o[f][j] * inv;
            const size_t off = (size_t)row * ED + h * HD + f * 16 + fr;
            const bf16 hv = (bf16)v;
            ch[off] = hv;
            cl[off] = (bf16)(v - (float)hv);
        }
    }
    if (fr == 0) {
#pragma unroll
        for (int j = 0; j < 4; ++j) {
            const int r = q0 + wave * 16 + fq * 4 + j;
            mrow[((size_t)n * NH + h) * SL + r] = mj[j];
            srow[((size_t)n * NH + h) * SL + r] = sj[j];
        }
    }
}

// ------------------- head-averaged weights v3: LDS-staged, reg accumulator -------------------
// Block = (qt: 64 q-rows, kt: 32 k-cols), all nn & h. Q/K tiles staged per (h,nn)
// via global_load_lds (linear dest + inverse-swizzled source), double-buffered.
// w = exp(a + t2), t2 = bias - m - ln(16 s) hoisted per (h,nn); mask folds to -1e30.
__global__ __launch_bounds__(256) void k_avg(
    const bf16* __restrict__ qh, const bf16* __restrict__ kh,
    const float* __restrict__ bias, const int* __restrict__ mask,
    const float* __restrict__ mrow, const float* __restrict__ srow,
    float* __restrict__ avg)
{
    __shared__ __attribute__((aligned(16))) bf16 Qs[2][64 * 64];  // 8KB x2
    __shared__ __attribute__((aligned(16))) bf16 Ks2[2][32 * 64]; // 4KB x2

    const int qt = blockIdx.x, kt = blockIdx.y;
    const int tid = threadIdx.x, wave = tid >> 6, lane = tid & 63;
    const int fr = lane & 15, fq = lane >> 4;
    const int frx = fr & 7;
    const int q0 = qt * 64, k0 = kt * 32;
    const int qr = q0 + wave * 16;
    const f32x4 z4 = {0.f, 0.f, 0.f, 0.f};

    // acc[nn][nf][j] -- all compile-time indices -> VGPRs
    f32x4 acc[4][2];
#pragma unroll
    for (int nn = 0; nn < 4; ++nn)
#pragma unroll
        for (int nf = 0; nf < 2; ++nf) acc[nn][nf] = z4;

    bool mk[4][2];
#pragma unroll
    for (int nn = 0; nn < 4; ++nn)
#pragma unroll
        for (int nf = 0; nf < 2; ++nf)
            mk[nn][nf] = mask[nn * SL + k0 + nf * 16 + fr] != 0;

    // stage helper: Q(nn,h) 64x64 (2 loads/thread) + K(nn,h) 32x64 (1 load/thread)
    auto stage = [&](int hh, int nn2, int b) {
        const bf16* qb = qh + (((size_t)nn2 * NH + hh) * SL + q0) * HD;
        const bf16* kb = kh + (((size_t)nn2 * NH + hh) * SL + k0) * HD;
#pragma unroll
        for (int i = 0; i < 2; ++i) {
            const int li = i * 256 + tid;
            const int r = li >> 3, s = li & 7;
            gl_lds16(qb + (size_t)r * HD + (s ^ (r & 7)) * 8,
                     &Qs[b][(i * 256 + wave * 64) * 8]);
        }
        {
            const int r = tid >> 3, s = tid & 7;
            gl_lds16(kb + (size_t)r * HD + (s ^ (r & 7)) * 8,
                     &Ks2[b][(wave * 64) * 8]);
        }
    };

    // prologue
    stage(0, 0, 0);
    __syncthreads();

    int cur = 0;
#pragma unroll 1
    for (int h = 0; h < NH; ++h) {
        // bias tile rows for this h (8 coalesced loads)
        float bfr[2][4];
#pragma unroll
        for (int nf = 0; nf < 2; ++nf)
#pragma unroll
            for (int j = 0; j < 4; ++j)
                bfr[nf][j] = bias[((size_t)h * SL + qr + fq * 4 + j) * SL + k0 + nf * 16 + fr];

#pragma unroll
        for (int nn = 0; nn < 4; ++nn) {
            const int ih = h * 4 + nn;
            const int nxt = cur ^ 1;
            if (ih < 63) stage((ih + 1) >> 2, (ih + 1) & 3, nxt);

            // row stats (vectorized 16B loads; 4 rows per thread via fq)
            const size_t sidx = ((size_t)nn * NH + h) * SL + qr + fq * 4;
            const f32x4 mv = *(const f32x4*)(mrow + sidx);
            const f32x4 sv = *(const f32x4*)(srow + sidx);
            float t2[2][4];
#pragma unroll
            for (int j = 0; j < 4; ++j) {
                const float lg = __logf(16.0f * sv[j]);
#pragma unroll
                for (int nf = 0; nf < 2; ++nf)
                    t2[nf][j] = mk[nn][nf] ? -1e30f : (bfr[nf][j] - mv[j] - lg);
            }

            // fragments from LDS (swizzled, conflict-free)
            const bf16* qp = &Qs[cur][(wave * 16 + fr) * 64];
            const bf16x8 qf0 = *(const bf16x8*)&qp[(fq ^ frx) * 8];
            const bf16x8 qf1 = *(const bf16x8*)&qp[((fq + 4) ^ frx) * 8];
#pragma unroll
            for (int nf = 0; nf < 2; ++nf) {
                const bf16* kp = &Ks2[cur][(nf * 16 + fr) * 64];
                const bf16x8 b0 = *(const bf16x8*)&kp[(fq ^ frx) * 8];
                const bf16x8 b1 = *(const bf16x8*)&kp[((fq + 4) ^ frx) * 8];
                f32x4 a = z4;
                a = MFMA16(qf0, b0, a);
                a = MFMA16(qf1, b1, a);
#pragma unroll
                for (int j = 0; j < 4; ++j)
                    acc[nn][nf][j] += __expf(a[j] + t2[nf][j]);
            }
            __syncthreads();
            cur = nxt;
        }
    }

    // writeback: coalesced 64B segments per (nn,j,nf)
#pragma unroll
    for (int nn = 0; nn < 4; ++nn)
#pragma unroll
        for (int j = 0; j < 4; ++j) {
            const size_t rowoff = ((size_t)nn * SL + qr + fq * 4 + j) * SL;
#pragma unroll
            for (int nf = 0; nf < 2; ++nf)
                avg[rowoff + k0 + nf * 16 + fr] = acc[nn][nf][j];
        }
}

// ------------------- launcher -------------------
extern "C" void kernel_launch(void* const* d_in, const int* in_sizes, int n_in,
                              void* d_out, int out_size, void* d_ws, size_t ws_size,
                              hipStream_t stream)
{
    (void)in_sizes; (void)n_in; (void)out_size; (void)ws_size;
    const float* query = (const float*)d_in[0];
    const float* bias  = (const float*)d_in[1];
    const int* mask = (const int*)d_in[2];
    const float* Wq = (const float*)d_in[3];
    const float* bq = (const float*)d_in[4];
    const float* Wk = (const float*)d_in[5];
    const float* bk = (const float*)d_in[6];
    const float* Wv = (const float*)d_in[7];
    const float* bv = (const float*)d_in[8];
    const float* Wo = (const float*)d_in[9];
    const float* bo = (const float*)d_in[10];
    float* out0 = (float*)d_out;                      // [N,L,E]
    float* out1 = out0 + (size_t)MR * ED;             // [N,L,L]

    char* p = (char*)d_ws;
    auto carve = [&](size_t bytes) {
        char* r = p;
        p += (bytes + 255) & ~(size_t)255;
        return r;
    };
    const size_t QKVB = (size_t)NB * NH * SL * HD * 2;   // 16.78 MB
    bf16* xh = (bf16*)carve((size_t)MR * ED * 2);
    bf16* xl = (bf16*)carve((size_t)MR * ED * 2);
    bf16* wh = (bf16*)carve((size_t)4 * ED * ED * 2);
    bf16* wl = (bf16*)carve((size_t)4 * ED * ED * 2);
    bf16* qh = (bf16*)carve(QKVB);
    bf16* kh = (bf16*)carve(QKVB);
    bf16* vh = (bf16*)carve(QKVB);
    float* mrow = (float*)carve((size_t)NB * NH * SL * 4);
    float* srow = (float*)carve((size_t)NB * NH * SL * 4);
    bf16* ch = (bf16*)carve((size_t)MR * ED * 2);
    bf16* cl = (bf16*)carve((size_t)MR * ED * 2);

    // 1. split inputs to hi/lo bf16
    {
        const int n4 = MR * ED / 4;
        k_split<<<(n4 + 255) / 256, 256, 0, stream>>>(query, xh, xl, n4);
        const int w4 = ED * ED / 4;
        const float* Ws4[4] = {Wq, Wk, Wv, Wo};
        for (int i = 0; i < 4; ++i)
            k_split<<<(w4 + 255) / 256, 256, 0, stream>>>(
                Ws4[i], wh + (size_t)i * ED * ED, wl + (size_t)i * ED * ED, w4);
    }
    // 2. QKV projections
    k_qkv_gemm<<<dim3(MR / 128, ED / 128, 3), 256, 0, stream>>>(
        xh, xl, wh, wl, bq, bk, bv, qh, kh, vh);
    // 3. flash attention + row stats + context
    k_flash<<<dim3(2048), 256, 0, stream>>>(
        qh, kh, vh, bias, mask, ch, cl, mrow, srow);
    // 4. head-averaged attention weights
    k_avg<<<dim3(SL / 64, SL / 32), 256, 0, stream>>>(
        qh, kh, bias, mask, mrow, srow, out1);
    // 5. output projection
    k_out_gemm<<<dim3(MR / 128, ED / 128), 256, 0, stream>>>(
        ch, cl, wh + (size_t)3 * ED * ED, wl + (size_t)3 * ED * ED, bo, out0);
}